// Round 17
// baseline (93.100 us; speedup 1.0000x reference)
//
#include <hip/hip_runtime.h>

#define N_SP 3136   // H*W = 49*64
#define C_CH 256
#define CQ   32
#define NB   4
#define JT   64     // attn j-tile
#define NJT  49     // j-tiles (exact)
#define QT   64     // attn q-tile (49 tiles exact)
// 1 / (exp(sqrt(3))*sqrt(3136/256) + 2*sqrt(6))
#define INV_BOUND 0.04051569f
#define LOG2E 1.44269504f

typedef __attribute__((ext_vector_type(8))) short bf16x8;
typedef __attribute__((ext_vector_type(4))) float f32x4;
typedef __attribute__((ext_vector_type(2))) long long l64x2;
typedef unsigned short u16;
typedef unsigned int   u32;
typedef unsigned char  u8;
typedef long long      l64;

#define MFMA16(a,b,c) __builtin_amdgcn_mfma_f32_16x16x32_bf16(a,b,c,0,0,0)
#define MFMA8(a,b,c)  __builtin_amdgcn_mfma_f32_16x16x32_bf8_fp8(a,b,c,0,0,0)

__device__ __forceinline__ u16 f2b(float f) {
    u32 u = __builtin_bit_cast(u32, f);
    u += 0x7fffu + ((u >> 16) & 1u);   // RTNE
    return (u16)(u >> 16);
}
__device__ __forceinline__ u8 f2fp8(float f) {
    return (u8)(__builtin_amdgcn_cvt_pk_fp8_f32(f, f, 0, false) & 0xff);
}
__device__ __forceinline__ void dma16(const void* g, void* l) {
    __builtin_amdgcn_global_load_lds((const __attribute__((address_space(1))) u32*)g,
                                     (__attribute__((address_space(3))) u32*)l, 16, 0, 0);
}

// ---------------------------------------------------------------------------
// stage1 (R16, verified): xT transpose pre-swizzled (XCD-affine decode),
// W->bf16 pre-swizzled, norm+scale+kmax0.
// ---------------------------------------------------------------------------
__global__ __launch_bounds__(256) void stage1_kernel(
    const float* __restrict__ x, const float* __restrict__ Wq,
    const float* __restrict__ Wk, const float* __restrict__ Wv,
    u8* __restrict__ xT, u8* __restrict__ Wqb, u8* __restrict__ Wkb,
    u8* __restrict__ Wvb, float* __restrict__ scale_out,
    float* __restrict__ kmax)
{
    __shared__ float smem[64 * 65];
    const int t = threadIdx.x;
    const int bid = blockIdx.x;

    if (bid < 784) {
        float (*tile)[65] = (float(*)[65])smem;
        const int xcd = bid & 7, slot = bid >> 3;
        const int b = xcd >> 1;
        const int i = slot * 2 + (xcd & 1);          // 0..195
        const int ct = i & 3, nt = i >> 2;           // 4 x 49
        const int c0 = ct * 64, n0 = nt * 64;
        const int cc = t >> 4, nn4 = (t & 15) * 4;
        #pragma unroll
        for (int k = 0; k < 4; ++k) {
            int cl = cc + k * 16;
            float4 v = *(const float4*)(x + (size_t)(b * C_CH + c0 + cl) * N_SP + n0 + nn4);
            tile[cl][nn4] = v.x; tile[cl][nn4 + 1] = v.y;
            tile[cl][nn4 + 2] = v.z; tile[cl][nn4 + 3] = v.w;
        }
        __syncthreads();
        const int c4 = (t & 15) * 4, nn = t >> 4;
        #pragma unroll
        for (int k = 0; k < 4; ++k) {
            int nl = nn + k * 16;
            ushort4 o;
            o.x = f2b(tile[c4 + 0][nl]); o.y = f2b(tile[c4 + 1][nl]);
            o.z = f2b(tile[c4 + 2][nl]); o.w = f2b(tile[c4 + 3][nl]);
            const int off = ((c0 + c4) * 2) ^ ((nl & 15) << 5);
            *(ushort4*)(xT + (size_t)(b * N_SP + n0 + nl) * 512 + off) = o;
        }
    } else if (bid < 864) {
        int idx = (bid - 784) * 256 + t;
        const float* src; u8* dst; int off;
        if (idx < 2048)      { src = Wq; dst = Wqb; off = idx; }
        else if (idx < 4096) { src = Wk; dst = Wkb; off = idx - 2048; }
        else                 { src = Wv; dst = Wvb; off = idx - 4096; }
        float4 v = *(const float4*)(src + off * 4);
        ushort4 o; o.x = f2b(v.x); o.y = f2b(v.y); o.z = f2b(v.z); o.w = f2b(v.w);
        const int row = off >> 6, inner = (off & 63) * 8;
        *(ushort4*)(dst + row * 512 + (inner ^ ((row & 15) << 5))) = o;
    } else {
        if (t < NB) kmax[t] = 0.f;
        float* red = smem;
        float u2 = 0.f;
        for (int i = t; i < CQ * C_CH; i += 256) { float w = Wq[i]; u2 += w * w; }
        red[t] = u2; __syncthreads();
        #pragma unroll
        for (int s = 128; s > 0; s >>= 1) { if (t < s) red[t] += red[t + s]; __syncthreads(); }
        float u2t = red[0]; __syncthreads();
        float vn2 = 0.f;
        for (int o = 0; o < CQ; ++o)   { float w = Wk[o * C_CH + t]; vn2 += w * w; }
        float wn2 = 0.f;
        for (int o = 0; o < C_CH; ++o) { float w = Wv[o * C_CH + t]; wn2 += w * w; }
        red[t] = fmaxf(vn2, wn2); __syncthreads();
        #pragma unroll
        for (int s = 128; s > 0; s >>= 1) { if (t < s) red[t] = fmaxf(red[t], red[t + s]); __syncthreads(); }
        if (t == 0) scale_out[0] = 1.0f / (sqrtf(u2t) * sqrtf(red[0]));
    }
}

// ---------------------------------------------------------------------------
// qkv (R16, verified): XCD-affine grid 984; DMA-staged x/W -> LDS -> MFMA.
// ---------------------------------------------------------------------------
__global__ __launch_bounds__(256) void qkv_mfma(
    const u8* __restrict__ xT, const u8* __restrict__ Wqb,
    const u8* __restrict__ Wkb, const u8* __restrict__ Wvb,
    const float* __restrict__ bq, const float* __restrict__ bk,
    const float* __restrict__ bv, const float* __restrict__ scale_p,
    u16* __restrict__ qT, u8* __restrict__ Kg, u8* __restrict__ Vg,
    float* __restrict__ qnorm, float* __restrict__ kmax)
{
    __shared__ __align__(16) u8 xTl[32768];
    __shared__ __align__(16) u8 Wl[32768];

    const int t = threadIdx.x;
    const int xcd = blockIdx.x & 7, slot = blockIdx.x >> 3;
    const int b = xcd >> 1;
    const int i = slot * 2 + (xcd & 1);
    if (i >= 245) return;
    const int split = i / 49, nt = i % 49;
    const int w = t >> 6, lane = t & 63, li = t & 15, g = (t >> 4) & 3;
    const int n = nt * 64 + w * 16 + li;
    const int r0 = (split - 1) * 64;
    const f32x4 zero = {0.f, 0.f, 0.f, 0.f};

    {
        const u8* xsrc = xT + (size_t)(b * N_SP + nt * 64) * 512;
        #pragma unroll
        for (int k = 0; k < 8; ++k)
            dma16(xsrc + w * 8192 + k * 1024 + lane * 16, xTl + w * 8192 + k * 1024);
        if (split == 0) {
            #pragma unroll
            for (int k = 0; k < 4; ++k)
                dma16(Wqb + w * 4096 + k * 1024 + lane * 16, Wl + w * 4096 + k * 1024);
            #pragma unroll
            for (int k = 0; k < 4; ++k)
                dma16(Wkb + w * 4096 + k * 1024 + lane * 16, Wl + 16384 + w * 4096 + k * 1024);
        } else {
            const u8* wsrc = Wvb + (size_t)r0 * 512;
            #pragma unroll
            for (int k = 0; k < 8; ++k)
                dma16(wsrc + w * 8192 + k * 1024 + lane * 16, Wl + w * 8192 + k * 1024);
        }
    }
    asm volatile("s_waitcnt vmcnt(0)" ::: "memory");
    __syncthreads();

    const int swz = li << 5;
    bf16x8 xf[8];
    #pragma unroll
    for (int ks = 0; ks < 8; ++ks)
        xf[ks] = *(const bf16x8*)(xTl + (w * 16 + li) * 512 + ((ks * 64 + 16 * g) ^ swz));

    if (split == 0) {
        f32x4 aq0 = zero, aq1 = zero, ak0 = zero, ak1 = zero;
        #pragma unroll
        for (int ks = 0; ks < 8; ++ks) {
            const int o = (ks * 64 + 16 * g) ^ swz;
            bf16x8 w0 = *(const bf16x8*)(Wl + li * 512 + o);
            bf16x8 w1 = *(const bf16x8*)(Wl + (16 + li) * 512 + o);
            bf16x8 w2 = *(const bf16x8*)(Wl + 16384 + li * 512 + o);
            bf16x8 w3 = *(const bf16x8*)(Wl + 16384 + (16 + li) * 512 + o);
            aq0 = MFMA16(w0, xf[ks], aq0);
            aq1 = MFMA16(w1, xf[ks], aq1);
            ak0 = MFMA16(w2, xf[ks], ak0);
            ak1 = MFMA16(w3, xf[ks], ak1);
        }
        const float scf = scale_p[0] * LOG2E;
        f32x4 bq0 = *(const f32x4*)(bq + 4 * g);
        f32x4 bq1 = *(const f32x4*)(bq + 16 + 4 * g);
        f32x4 bk0 = *(const f32x4*)(bk + 4 * g);
        f32x4 bk1 = *(const f32x4*)(bk + 16 + 4 * g);
        float qn2 = 0.f, kn2 = 0.f;
        ushort4 s0, s1;
        #pragma unroll
        for (int r = 0; r < 4; ++r) {
            float q0 = (aq0[r] + bq0[r]) * scf;
            float q1 = (aq1[r] + bq1[r]) * scf;
            qn2 += q0 * q0 + q1 * q1;
            ((u16*)&s0)[r] = f2b(q0); ((u16*)&s1)[r] = f2b(q1);
        }
        *(ushort4*)(qT + (size_t)(b * N_SP + n) * CQ + 4 * g)      = s0;
        *(ushort4*)(qT + (size_t)(b * N_SP + n) * CQ + 16 + 4 * g) = s1;
        #pragma unroll
        for (int r = 0; r < 4; ++r) {
            float k0 = ak0[r] + bk0[r];
            float k1 = ak1[r] + bk1[r];
            kn2 += k0 * k0 + k1 * k1;
            ((u16*)&s0)[r] = f2b(k0); ((u16*)&s1)[r] = f2b(k1);
        }
        u8* krow = Kg + ((size_t)b * N_SP + n) * 64;
        const int swn = ((n >> 1) & 3) << 4;
        *(ushort4*)(krow + ((8 * g) ^ swn))      = s0;
        *(ushort4*)(krow + ((32 + 8 * g) ^ swn)) = s1;

        qn2 += __shfl_xor(qn2, 16); qn2 += __shfl_xor(qn2, 32);
        kn2 += __shfl_xor(kn2, 16); kn2 += __shfl_xor(kn2, 32);
        if (g == 0) qnorm[b * N_SP + n] = sqrtf(qn2);
        float kn = sqrtf(kn2);
        #pragma unroll
        for (int d = 1; d < 16; d <<= 1) kn = fmaxf(kn, __shfl_xor(kn, d));
        if ((t & 63) == 0) atomicMax((int*)(kmax + b), __float_as_int(kn));
    } else {
        f32x4 a[4] = {zero, zero, zero, zero};
        #pragma unroll
        for (int ks = 0; ks < 8; ++ks) {
            const int o = (ks * 64 + 16 * g) ^ swz;
            #pragma unroll
            for (int fr = 0; fr < 4; ++fr) {
                bf16x8 wf = *(const bf16x8*)(Wl + (fr * 16 + li) * 512 + o);
                a[fr] = MFMA16(wf, xf[ks], a[fr]);
            }
        }
        const int jj = w * 16 + li;
        const int p = ((jj >> 5) & 1) * 8 + ((jj >> 3) & 3) * 16 + (jj & 7);
        u8* vtile = Vg + (size_t)(b * NJT + nt) * 16384;
        #pragma unroll
        for (int fr = 0; fr < 4; ++fr) {
            f32x4 bb = *(const f32x4*)(bv + r0 + fr * 16 + 4 * g);
            #pragma unroll
            for (int r = 0; r < 4; ++r) {
                const int c = r0 + fr * 16 + 4 * g + r;
                vtile[c * 64 + (p ^ (((c >> 1) & 3) << 4))] = f2fp8(a[fr][r] + bb[r]);
            }
        }
    }
}

// ---------------------------------------------------------------------------
// Attention: 392 blocks (4b x 49qt x 2 ch-halves) x 512 thr. Channel-split:
// block computes out channels [128h,128h+128) over ALL j (S/ls recomputed
// per half -> no combine kernel). Ring-3 depth-2 DMA, 12 dma16/iter
// (V 8KB half-tile + K 4KB), per-wave counted vmcnt. 40KB LDS -> 2-3 blk/CU.
// ---------------------------------------------------------------------------
__global__ __launch_bounds__(512, 6) void attn_mfma(
    const u16* __restrict__ qT, const u8* __restrict__ Kg,
    const u8* __restrict__ Vg, const float* __restrict__ x,
    const float* __restrict__ gamma_p, const float* __restrict__ qnorm,
    const float* __restrict__ kmax, float* __restrict__ out)
{
    __shared__ __align__(16) u8 smem[40960];
    u8* const Vl = smem;             // 3 x 8192
    u8* const Kl = smem + 24576;     // 3 x 4096
    u8* const Pl = smem + 36864;     // 4096 (reduce overlays here after loop)

    const int t = threadIdx.x;
    const int w = t >> 6, li = t & 15, g = (t >> 4) & 3;
    const int jh = w & 3, qh = w >> 2;
    const int swz = ((li >> 1) & 3) << 4;

    const int bid = blockIdx.x;                  // 392 = 4b x 49qt x 2h
    const int b = bid / 98, rem = bid % 98;
    const int qt = rem >> 1, h = rem & 1;
    const int i0 = qt * QT;

    const u16* qTb = qT + (size_t)b * N_SP * CQ;
    const u8*  Kbb = Kg + (size_t)b * N_SP * 64;
    const u8*  Vbb = Vg + (size_t)b * NJT * 16384 + h * 8192;
    const float kmb = kmax[b];
    const f32x4 zero = {0.f, 0.f, 0.f, 0.f};

    const int qA = 2 * qh, qB = 2 * qh + 1;
    const bf16x8 qfA = *(const bf16x8*)(qTb + (size_t)(i0 + qA * 16 + li) * CQ + 8 * g);
    const bf16x8 qfB = *(const bf16x8*)(qTb + (size_t)(i0 + qB * 16 + li) * CQ + 8 * g);
    const float mrA = qnorm[b * N_SP + i0 + qA * 16 + li] * kmb;
    const float mrB = qnorm[b * N_SP + i0 + qB * 16 + li] * kmb;

    f32x4 acc[4];
    #pragma unroll
    for (int qq = 0; qq < 4; ++qq) acc[qq] = zero;
    float lsA = 0.f, lsB = 0.f;

    // 12 dma16 per tile: V half-tile 8KB (all 8 waves, 1 each), K 4KB (waves
    // 0-3, 1 each). vmcnt: waves 0-3 own 2 instr/ISSUE, waves 4-7 own 1.
    #define ISSUE(jt_, s_) do {                                               \
        dma16(Vbb + (size_t)(jt_) * 16384 + t * 16,                           \
              Vl + (s_) * 8192 + w * 1024);                                   \
        if (t < 256)                                                          \
            dma16(Kbb + (size_t)(jt_) * 4096 + t * 16,                        \
                  Kl + (s_) * 4096 + w * 1024);                               \
    } while (0)

    ISSUE(0, 0);
    ISSUE(1, 1);

    // P write byte position: j' = jh*16 + 4g + r
    const int p0 = ((jh >> 1) & 1) * 8 + ((jh * 2 + (g >> 1)) & 3) * 16 + 4 * (g & 1);

    int cur = 0;
    for (int it = 0; it < NJT; ++it) {
        if (w < 4) asm volatile("s_waitcnt vmcnt(2) lgkmcnt(0)" ::: "memory");
        else       asm volatile("s_waitcnt vmcnt(1) lgkmcnt(0)" ::: "memory");
        __builtin_amdgcn_s_barrier();
        asm volatile("" ::: "memory");

        {
            int jn = it + 2; if (jn > NJT - 1) jn = NJT - 1;
            int s2 = cur + 2; if (s2 >= 3) s2 -= 3;
            ISSUE(jn, s2);
        }

        // ---- S^T: j-frag jh x q-frags {qA, qB} ----
        const u8* Kc = Kl + cur * 4096;
        bf16x8 kf = *(const bf16x8*)(Kc + (jh * 16 + li) * 64 + ((16 * g) ^ swz));
        f32x4 sA = MFMA16(kf, qfA, zero);
        f32x4 sB = MFMA16(kf, qfB, zero);
        {
            float a0 = exp2f(sA[0] - mrA), a1 = exp2f(sA[1] - mrA);
            float a2 = exp2f(sA[2] - mrA), a3 = exp2f(sA[3] - mrA);
            lsA += (a0 + a1) + (a2 + a3);
            int pk = __builtin_amdgcn_cvt_pk_bf8_f32(a0, a1, 0, false);
            pk = __builtin_amdgcn_cvt_pk_bf8_f32(a2, a3, pk, true);
            *(u32*)(Pl + (qA * 16 + li) * 64 + (p0 ^ swz)) = (u32)pk;
            float b0 = exp2f(sB[0] - mrB), b1 = exp2f(sB[1] - mrB);
            float b2 = exp2f(sB[2] - mrB), b3 = exp2f(sB[3] - mrB);
            lsB += (b0 + b1) + (b2 + b3);
            pk = __builtin_amdgcn_cvt_pk_bf8_f32(b0, b1, 0, false);
            pk = __builtin_amdgcn_cvt_pk_bf8_f32(b2, b3, pk, true);
            *(u32*)(Pl + (qB * 16 + li) * 64 + (p0 ^ swz)) = (u32)pk;
        }
        asm volatile("s_waitcnt lgkmcnt(0)" ::: "memory");
        __builtin_amdgcn_s_barrier();
        asm volatile("" ::: "memory");

        // ---- PV: 4 q-frags x this wave's 16 ch (b128 = both ks) ----
        const u8* Vc = Vl + cur * 8192;
        __builtin_amdgcn_s_setprio(1);
        l64x2 pa0 = *(const l64x2*)(Pl + (0 * 16 + li) * 64 + ((16 * g) ^ swz));
        l64x2 pa1 = *(const l64x2*)(Pl + (1 * 16 + li) * 64 + ((16 * g) ^ swz));
        l64x2 pa2 = *(const l64x2*)(Pl + (2 * 16 + li) * 64 + ((16 * g) ^ swz));
        l64x2 pa3 = *(const l64x2*)(Pl + (3 * 16 + li) * 64 + ((16 * g) ^ swz));
        l64x2 v0  = *(const l64x2*)(Vc + (w * 16 + li) * 64 + ((16 * g) ^ swz));
        acc[0] = MFMA8(pa0[0], v0[0], acc[0]);
        acc[1] = MFMA8(pa1[0], v0[0], acc[1]);
        acc[2] = MFMA8(pa2[0], v0[0], acc[2]);
        acc[3] = MFMA8(pa3[0], v0[0], acc[3]);
        acc[0] = MFMA8(pa0[1], v0[1], acc[0]);
        acc[1] = MFMA8(pa1[1], v0[1], acc[1]);
        acc[2] = MFMA8(pa2[1], v0[1], acc[2]);
        acc[3] = MFMA8(pa3[1], v0[1], acc[3]);
        __builtin_amdgcn_s_setprio(0);

        ++cur; if (cur == 3) cur = 0;
    }
    #undef ISSUE

    // ---- denominators (reduce buffers overlay P region) ----
    lsA += __shfl_xor(lsA, 16); lsA += __shfl_xor(lsA, 32);
    lsB += __shfl_xor(lsB, 16); lsB += __shfl_xor(lsB, 32);
    __syncthreads();
    float* red       = (float*)Pl;
    float* red_final = (float*)(Pl + 1024);
    if ((t & 63) < 16) {
        red[w * 32 + li]      = lsA;
        red[w * 32 + 16 + li] = lsB;
    }
    __syncthreads();
    if (t < 64) {
        const int hh = t >> 4, l2 = t & 15;
        float s = 0.f;
        #pragma unroll
        for (int jw = 0; jw < 4; ++jw)
            s += red[((hh >> 1) * 4 + jw) * 32 + (hh & 1) * 16 + l2];
        red_final[t] = s;
    }
    __syncthreads();

    // ---- epilogue: this half's 128 channels ----
    const float gsc = gamma_p[0] * INV_BOUND;
    const int c = h * 128 + w * 16 + li;
    #pragma unroll
    for (int qq = 0; qq < 4; ++qq) {
        f32x4 lsv = *(const f32x4*)(red_final + qq * 16 + 4 * g);
        f32x4 rinv;
        #pragma unroll
        for (int r = 0; r < 4; ++r) rinv[r] = gsc / lsv[r];
        const size_t base = ((size_t)b * C_CH + c) * N_SP + i0 + qq * 16 + 4 * g;
        float4 xv = *(const float4*)(x + base);
        float4 o;
        o.x = acc[qq][0] * rinv[0] + xv.x;
        o.y = acc[qq][1] * rinv[1] + xv.y;
        o.z = acc[qq][2] * rinv[2] + xv.z;
        o.w = acc[qq][3] * rinv[3] + xv.w;
        *(float4*)(out + base) = o;
    }
}

// ---------------------------------------------------------------------------
extern "C" void kernel_launch(void* const* d_in, const int* in_sizes, int n_in,
                              void* d_out, int out_size, void* d_ws, size_t ws_size,
                              hipStream_t stream)
{
    const float* x  = (const float*)d_in[0];
    const float* Wq = (const float*)d_in[1];
    const float* bq = (const float*)d_in[2];
    const float* Wk = (const float*)d_in[3];
    const float* bk = (const float*)d_in[4];
    const float* Wv = (const float*)d_in[5];
    const float* bv = (const float*)d_in[6];
    const float* gm = (const float*)d_in[7];
    float* out = (float*)d_out;
    float* ws  = (float*)d_ws;

    float* scale = ws;                       // [0..3]
    float* kmax  = ws + 4;                   // [4..7]
    float* qnorm = ws + 8;                   // NB*N_SP
    u8* Wqb = (u8*)(ws + 8 + NB * N_SP);     // 16B-aligned
    u8* Wkb = Wqb + 32 * 512;
    u8* Wvb = Wkb + 32 * 512;
    u8* xT  = Wvb + 256 * 512;
    u16* qT = (u16*)(xT + (size_t)NB * N_SP * 512);
    u8* Kg  = (u8*)(qT + (size_t)NB * N_SP * CQ);
    u8* Vg  = Kg + (size_t)NB * N_SP * 64;

    stage1_kernel<<<865, 256, 0, stream>>>(x, Wq, Wk, Wv, xT, Wqb, Wkb, Wvb, scale, kmax);
    qkv_mfma<<<984, 256, 0, stream>>>(xT, Wqb, Wkb, Wvb, bq, bk, bv, scale, qT, Kg, Vg, qnorm, kmax);
    attn_mfma<<<392, 512, 0, stream>>>(qT, Kg, Vg, x, gm, qnorm, kmax, out);
}

// Round 18
// 85.575 us; speedup vs baseline: 1.0879x; 1.0879x over previous
//
#include <hip/hip_runtime.h>

#define N_SP 3136   // H*W = 49*64
#define C_CH 256
#define CQ   32
#define NB   4
#define JT   64     // attn j-tile
#define NJT  49     // j-tiles (exact)
#define QT   64     // attn q-tile (49 tiles exact)
// 1 / (exp(sqrt(3))*sqrt(3136/256) + 2*sqrt(6))
#define INV_BOUND 0.04051569f
#define LOG2E 1.44269504f

typedef __attribute__((ext_vector_type(8))) short bf16x8;
typedef __attribute__((ext_vector_type(4))) float f32x4;
typedef __attribute__((ext_vector_type(2))) long long l64x2;
typedef unsigned short u16;
typedef unsigned int   u32;
typedef unsigned char  u8;
typedef long long      l64;

#define MFMA16(a,b,c) __builtin_amdgcn_mfma_f32_16x16x32_bf16(a,b,c,0,0,0)
#define MFMA8(a,b,c)  __builtin_amdgcn_mfma_f32_16x16x32_bf8_fp8(a,b,c,0,0,0)

__device__ __forceinline__ u16 f2b(float f) {
    u32 u = __builtin_bit_cast(u32, f);
    u += 0x7fffu + ((u >> 16) & 1u);   // RTNE
    return (u16)(u >> 16);
}
__device__ __forceinline__ u8 f2fp8(float f) {
    return (u8)(__builtin_amdgcn_cvt_pk_fp8_f32(f, f, 0, false) & 0xff);
}
__device__ __forceinline__ void dma16(const void* g, void* l) {
    __builtin_amdgcn_global_load_lds((const __attribute__((address_space(1))) u32*)g,
                                     (__attribute__((address_space(3))) u32*)l, 16, 0, 0);
}

// ---------------------------------------------------------------------------
// stage1 (verified): xT transpose pre-swizzled, W->bf16 pre-swizzled,
// norm+scale+kmax0.
// ---------------------------------------------------------------------------
__global__ __launch_bounds__(256) void stage1_kernel(
    const float* __restrict__ x, const float* __restrict__ Wq,
    const float* __restrict__ Wk, const float* __restrict__ Wv,
    u8* __restrict__ xT, u8* __restrict__ Wqb, u8* __restrict__ Wkb,
    u8* __restrict__ Wvb, float* __restrict__ scale_out,
    float* __restrict__ kmax)
{
    __shared__ float smem[64 * 65];
    const int t = threadIdx.x;
    const int bid = blockIdx.x;

    if (bid < 784) {
        float (*tile)[65] = (float(*)[65])smem;
        const int xcd = bid & 7, slot = bid >> 3;
        const int b = xcd >> 1;
        const int i = slot * 2 + (xcd & 1);          // 0..195
        const int ct = i & 3, nt = i >> 2;           // 4 x 49
        const int c0 = ct * 64, n0 = nt * 64;
        const int cc = t >> 4, nn4 = (t & 15) * 4;
        #pragma unroll
        for (int k = 0; k < 4; ++k) {
            int cl = cc + k * 16;
            float4 v = *(const float4*)(x + (size_t)(b * C_CH + c0 + cl) * N_SP + n0 + nn4);
            tile[cl][nn4] = v.x; tile[cl][nn4 + 1] = v.y;
            tile[cl][nn4 + 2] = v.z; tile[cl][nn4 + 3] = v.w;
        }
        __syncthreads();
        const int c4 = (t & 15) * 4, nn = t >> 4;
        #pragma unroll
        for (int k = 0; k < 4; ++k) {
            int nl = nn + k * 16;
            ushort4 o;
            o.x = f2b(tile[c4 + 0][nl]); o.y = f2b(tile[c4 + 1][nl]);
            o.z = f2b(tile[c4 + 2][nl]); o.w = f2b(tile[c4 + 3][nl]);
            const int off = ((c0 + c4) * 2) ^ ((nl & 15) << 5);
            *(ushort4*)(xT + (size_t)(b * N_SP + n0 + nl) * 512 + off) = o;
        }
    } else if (bid < 864) {
        int idx = (bid - 784) * 256 + t;
        const float* src; u8* dst; int off;
        if (idx < 2048)      { src = Wq; dst = Wqb; off = idx; }
        else if (idx < 4096) { src = Wk; dst = Wkb; off = idx - 2048; }
        else                 { src = Wv; dst = Wvb; off = idx - 4096; }
        float4 v = *(const float4*)(src + off * 4);
        ushort4 o; o.x = f2b(v.x); o.y = f2b(v.y); o.z = f2b(v.z); o.w = f2b(v.w);
        const int row = off >> 6, inner = (off & 63) * 8;
        *(ushort4*)(dst + row * 512 + (inner ^ ((row & 15) << 5))) = o;
    } else {
        if (t < NB) kmax[t] = 0.f;
        float* red = smem;
        float u2 = 0.f;
        for (int i = t; i < CQ * C_CH; i += 256) { float w = Wq[i]; u2 += w * w; }
        red[t] = u2; __syncthreads();
        #pragma unroll
        for (int s = 128; s > 0; s >>= 1) { if (t < s) red[t] += red[t + s]; __syncthreads(); }
        float u2t = red[0]; __syncthreads();
        float vn2 = 0.f;
        for (int o = 0; o < CQ; ++o)   { float w = Wk[o * C_CH + t]; vn2 += w * w; }
        float wn2 = 0.f;
        for (int o = 0; o < C_CH; ++o) { float w = Wv[o * C_CH + t]; wn2 += w * w; }
        red[t] = fmaxf(vn2, wn2); __syncthreads();
        #pragma unroll
        for (int s = 128; s > 0; s >>= 1) { if (t < s) red[t] = fmaxf(red[t], red[t + s]); __syncthreads(); }
        if (t == 0) scale_out[0] = 1.0f / (sqrtf(u2t) * sqrtf(red[0]));
    }
}

// ---------------------------------------------------------------------------
// qkv (verified): XCD-affine grid 984; DMA-staged x/W -> LDS -> MFMA.
// ---------------------------------------------------------------------------
__global__ __launch_bounds__(256) void qkv_mfma(
    const u8* __restrict__ xT, const u8* __restrict__ Wqb,
    const u8* __restrict__ Wkb, const u8* __restrict__ Wvb,
    const float* __restrict__ bq, const float* __restrict__ bk,
    const float* __restrict__ bv, const float* __restrict__ scale_p,
    u16* __restrict__ qT, u8* __restrict__ Kg, u8* __restrict__ Vg,
    float* __restrict__ qnorm, float* __restrict__ kmax)
{
    __shared__ __align__(16) u8 xTl[32768];
    __shared__ __align__(16) u8 Wl[32768];

    const int t = threadIdx.x;
    const int xcd = blockIdx.x & 7, slot = blockIdx.x >> 3;
    const int b = xcd >> 1;
    const int i = slot * 2 + (xcd & 1);
    if (i >= 245) return;
    const int split = i / 49, nt = i % 49;
    const int w = t >> 6, lane = t & 63, li = t & 15, g = (t >> 4) & 3;
    const int n = nt * 64 + w * 16 + li;
    const int r0 = (split - 1) * 64;
    const f32x4 zero = {0.f, 0.f, 0.f, 0.f};

    {
        const u8* xsrc = xT + (size_t)(b * N_SP + nt * 64) * 512;
        #pragma unroll
        for (int k = 0; k < 8; ++k)
            dma16(xsrc + w * 8192 + k * 1024 + lane * 16, xTl + w * 8192 + k * 1024);
        if (split == 0) {
            #pragma unroll
            for (int k = 0; k < 4; ++k)
                dma16(Wqb + w * 4096 + k * 1024 + lane * 16, Wl + w * 4096 + k * 1024);
            #pragma unroll
            for (int k = 0; k < 4; ++k)
                dma16(Wkb + w * 4096 + k * 1024 + lane * 16, Wl + 16384 + w * 4096 + k * 1024);
        } else {
            const u8* wsrc = Wvb + (size_t)r0 * 512;
            #pragma unroll
            for (int k = 0; k < 8; ++k)
                dma16(wsrc + w * 8192 + k * 1024 + lane * 16, Wl + w * 8192 + k * 1024);
        }
    }
    asm volatile("s_waitcnt vmcnt(0)" ::: "memory");
    __syncthreads();

    const int swz = li << 5;
    bf16x8 xf[8];
    #pragma unroll
    for (int ks = 0; ks < 8; ++ks)
        xf[ks] = *(const bf16x8*)(xTl + (w * 16 + li) * 512 + ((ks * 64 + 16 * g) ^ swz));

    if (split == 0) {
        f32x4 aq0 = zero, aq1 = zero, ak0 = zero, ak1 = zero;
        #pragma unroll
        for (int ks = 0; ks < 8; ++ks) {
            const int o = (ks * 64 + 16 * g) ^ swz;
            bf16x8 w0 = *(const bf16x8*)(Wl + li * 512 + o);
            bf16x8 w1 = *(const bf16x8*)(Wl + (16 + li) * 512 + o);
            bf16x8 w2 = *(const bf16x8*)(Wl + 16384 + li * 512 + o);
            bf16x8 w3 = *(const bf16x8*)(Wl + 16384 + (16 + li) * 512 + o);
            aq0 = MFMA16(w0, xf[ks], aq0);
            aq1 = MFMA16(w1, xf[ks], aq1);
            ak0 = MFMA16(w2, xf[ks], ak0);
            ak1 = MFMA16(w3, xf[ks], ak1);
        }
        const float scf = scale_p[0] * LOG2E;
        f32x4 bq0 = *(const f32x4*)(bq + 4 * g);
        f32x4 bq1 = *(const f32x4*)(bq + 16 + 4 * g);
        f32x4 bk0 = *(const f32x4*)(bk + 4 * g);
        f32x4 bk1 = *(const f32x4*)(bk + 16 + 4 * g);
        float qn2 = 0.f, kn2 = 0.f;
        ushort4 s0, s1;
        #pragma unroll
        for (int r = 0; r < 4; ++r) {
            float q0 = (aq0[r] + bq0[r]) * scf;
            float q1 = (aq1[r] + bq1[r]) * scf;
            qn2 += q0 * q0 + q1 * q1;
            ((u16*)&s0)[r] = f2b(q0); ((u16*)&s1)[r] = f2b(q1);
        }
        *(ushort4*)(qT + (size_t)(b * N_SP + n) * CQ + 4 * g)      = s0;
        *(ushort4*)(qT + (size_t)(b * N_SP + n) * CQ + 16 + 4 * g) = s1;
        #pragma unroll
        for (int r = 0; r < 4; ++r) {
            float k0 = ak0[r] + bk0[r];
            float k1 = ak1[r] + bk1[r];
            kn2 += k0 * k0 + k1 * k1;
            ((u16*)&s0)[r] = f2b(k0); ((u16*)&s1)[r] = f2b(k1);
        }
        u8* krow = Kg + ((size_t)b * N_SP + n) * 64;
        const int swn = ((n >> 1) & 3) << 4;
        *(ushort4*)(krow + ((8 * g) ^ swn))      = s0;
        *(ushort4*)(krow + ((32 + 8 * g) ^ swn)) = s1;

        qn2 += __shfl_xor(qn2, 16); qn2 += __shfl_xor(qn2, 32);
        kn2 += __shfl_xor(kn2, 16); kn2 += __shfl_xor(kn2, 32);
        if (g == 0) qnorm[b * N_SP + n] = sqrtf(qn2);
        float kn = sqrtf(kn2);
        #pragma unroll
        for (int d = 1; d < 16; d <<= 1) kn = fmaxf(kn, __shfl_xor(kn, d));
        if ((t & 63) == 0) atomicMax((int*)(kmax + b), __float_as_int(kn));
    } else {
        f32x4 a[4] = {zero, zero, zero, zero};
        #pragma unroll
        for (int ks = 0; ks < 8; ++ks) {
            const int o = (ks * 64 + 16 * g) ^ swz;
            #pragma unroll
            for (int fr = 0; fr < 4; ++fr) {
                bf16x8 wf = *(const bf16x8*)(Wl + (fr * 16 + li) * 512 + o);
                a[fr] = MFMA16(wf, xf[ks], a[fr]);
            }
        }
        const int jj = w * 16 + li;
        const int p = ((jj >> 5) & 1) * 8 + ((jj >> 3) & 3) * 16 + (jj & 7);
        u8* vtile = Vg + (size_t)(b * NJT + nt) * 16384;
        #pragma unroll
        for (int fr = 0; fr < 4; ++fr) {
            f32x4 bb = *(const f32x4*)(bv + r0 + fr * 16 + 4 * g);
            #pragma unroll
            for (int r = 0; r < 4; ++r) {
                const int c = r0 + fr * 16 + 4 * g + r;
                vtile[c * 64 + (p ^ (((c >> 1) & 3) << 4))] = f2fp8(a[fr][r] + bb[r]);
            }
        }
    }
}

// ---------------------------------------------------------------------------
// Attention: 196 blocks (4b x 49qt) x 1024 thr (16 waves). No j-split, no
// combine. Wave (qh=w>>2, jh=w&3): S^T = 1 MFMA16 (q-frag qh x j-frag jh);
// PV: 4 q-frags x 16 ch (8 MFMA8). Ring-4 depth-3 DMA, 20 dma16/iter
// (V 1/thread + K waves 0-3), per-wave counted vmcnt. LDS 84KB.
// ---------------------------------------------------------------------------
__global__ __launch_bounds__(1024) void attn_mfma(
    const u16* __restrict__ qT, const u8* __restrict__ Kg,
    const u8* __restrict__ Vg, const float* __restrict__ x,
    const float* __restrict__ gamma_p, const float* __restrict__ qnorm,
    const float* __restrict__ kmax, float* __restrict__ out)
{
    __shared__ __align__(16) u8 smem[86016];
    u8* const Vl = smem;             // 4 x 16384
    u8* const Kl = smem + 65536;     // 4 x 4096
    u8* const Pl = smem + 81920;     // 4096 (reduce overlays after loop)

    const int t = threadIdx.x;
    const int w = t >> 6, li = t & 15, g = (t >> 4) & 3;
    const int jh = w & 3, qh = w >> 2;               // qh 0..3, jh 0..3
    const int swz = ((li >> 1) & 3) << 4;

    const int b  = blockIdx.x / NJT;
    const int qt = blockIdx.x % NJT;
    const int i0 = qt * QT;

    const u16* qTb = qT + (size_t)b * N_SP * CQ;
    const u8*  Kbb = Kg + (size_t)b * N_SP * 64;
    const u8*  Vbb = Vg + (size_t)b * NJT * 16384;
    const float kmb = kmax[b];
    const f32x4 zero = {0.f, 0.f, 0.f, 0.f};

    const bf16x8 qf = *(const bf16x8*)(qTb + (size_t)(i0 + qh * 16 + li) * CQ + 8 * g);
    const float  mr = qnorm[b * N_SP + i0 + qh * 16 + li] * kmb;

    f32x4 acc[4];
    #pragma unroll
    for (int qq = 0; qq < 4; ++qq) acc[qq] = zero;
    float ls = 0.f;

    // 20 dma16 per tile: V 16KB (1/thread), K 4KB (waves 0-3, 1/thread).
    #define ISSUE(jt_, s_) do {                                               \
        dma16(Vbb + (size_t)(jt_) * 16384 + t * 16,                           \
              Vl + (s_) * 16384 + w * 1024);                                  \
        if (t < 256)                                                          \
            dma16(Kbb + (size_t)(jt_) * 4096 + t * 16,                        \
                  Kl + (s_) * 4096 + w * 1024);                               \
    } while (0)

    ISSUE(0, 0);
    ISSUE(1, 1);
    ISSUE(2, 2);

    // P write byte position: j' = jh*16 + 4g (+r)
    const int p0 = ((jh >> 1) & 1) * 8 + ((jh * 2 + (g >> 1)) & 3) * 16 + 4 * (g & 1);

    for (int it = 0; it < NJT; ++it) {
        const int cur = it & 3;
        if (w < 4) asm volatile("s_waitcnt vmcnt(4) lgkmcnt(0)" ::: "memory");
        else       asm volatile("s_waitcnt vmcnt(2) lgkmcnt(0)" ::: "memory");
        __builtin_amdgcn_s_barrier();
        asm volatile("" ::: "memory");

        {
            int jn = it + 3; if (jn > NJT - 1) jn = NJT - 1;
            ISSUE(jn, (cur + 3) & 3);
        }

        // ---- S^T: j-frag jh x q-frag qh (one MFMA16) ----
        const u8* Kc = Kl + cur * 4096;
        bf16x8 kf = *(const bf16x8*)(Kc + (jh * 16 + li) * 64 + ((16 * g) ^ swz));
        f32x4 s = MFMA16(kf, qf, zero);
        {
            float a0 = exp2f(s[0] - mr), a1 = exp2f(s[1] - mr);
            float a2 = exp2f(s[2] - mr), a3 = exp2f(s[3] - mr);
            ls += (a0 + a1) + (a2 + a3);
            int pk = __builtin_amdgcn_cvt_pk_bf8_f32(a0, a1, 0, false);
            pk = __builtin_amdgcn_cvt_pk_bf8_f32(a2, a3, pk, true);
            *(u32*)(Pl + (qh * 16 + li) * 64 + (p0 ^ swz)) = (u32)pk;
        }
        asm volatile("s_waitcnt lgkmcnt(0)" ::: "memory");
        __builtin_amdgcn_s_barrier();
        asm volatile("" ::: "memory");

        // ---- PV: 4 q-frags x this wave's 16 ch (b128 = both ks) ----
        const u8* Vc = Vl + cur * 16384;
        __builtin_amdgcn_s_setprio(1);
        l64x2 pa0 = *(const l64x2*)(Pl + (0 * 16 + li) * 64 + ((16 * g) ^ swz));
        l64x2 pa1 = *(const l64x2*)(Pl + (1 * 16 + li) * 64 + ((16 * g) ^ swz));
        l64x2 pa2 = *(const l64x2*)(Pl + (2 * 16 + li) * 64 + ((16 * g) ^ swz));
        l64x2 pa3 = *(const l64x2*)(Pl + (3 * 16 + li) * 64 + ((16 * g) ^ swz));
        l64x2 v0  = *(const l64x2*)(Vc + (w * 16 + li) * 64 + ((16 * g) ^ swz));
        acc[0] = MFMA8(pa0[0], v0[0], acc[0]);
        acc[1] = MFMA8(pa1[0], v0[0], acc[1]);
        acc[2] = MFMA8(pa2[0], v0[0], acc[2]);
        acc[3] = MFMA8(pa3[0], v0[0], acc[3]);
        acc[0] = MFMA8(pa0[1], v0[1], acc[0]);
        acc[1] = MFMA8(pa1[1], v0[1], acc[1]);
        acc[2] = MFMA8(pa2[1], v0[1], acc[2]);
        acc[3] = MFMA8(pa3[1], v0[1], acc[3]);
        __builtin_amdgcn_s_setprio(0);
    }
    #undef ISSUE

    // ---- denominators (reduce buffers overlay P region) ----
    ls += __shfl_xor(ls, 16); ls += __shfl_xor(ls, 32);
    __syncthreads();
    float* red       = (float*)Pl;           // [16 waves][16 q]
    float* red_final = (float*)(Pl + 1024);  // [64 q]
    if ((t & 63) < 16) red[w * 16 + li] = ls;
    __syncthreads();
    if (t < 64) {
        const int qh2 = t >> 4, l2 = t & 15;
        float s = red[(qh2 * 4 + 0) * 16 + l2] + red[(qh2 * 4 + 1) * 16 + l2]
                + red[(qh2 * 4 + 2) * 16 + l2] + red[(qh2 * 4 + 3) * 16 + l2];
        red_final[t] = s;
    }
    __syncthreads();

    // ---- epilogue: wave w -> channels w*16..w*16+15, 4 q-frags ----
    const float gsc = gamma_p[0] * INV_BOUND;
    const int c = w * 16 + li;
    #pragma unroll
    for (int qq = 0; qq < 4; ++qq) {
        f32x4 lsv = *(const f32x4*)(red_final + qq * 16 + 4 * g);
        f32x4 rinv;
        #pragma unroll
        for (int r = 0; r < 4; ++r) rinv[r] = gsc / lsv[r];
        const size_t base = ((size_t)b * C_CH + c) * N_SP + i0 + qq * 16 + 4 * g;
        float4 xv = *(const float4*)(x + base);
        float4 o;
        o.x = acc[qq][0] * rinv[0] + xv.x;
        o.y = acc[qq][1] * rinv[1] + xv.y;
        o.z = acc[qq][2] * rinv[2] + xv.z;
        o.w = acc[qq][3] * rinv[3] + xv.w;
        *(float4*)(out + base) = o;
    }
}

// ---------------------------------------------------------------------------
extern "C" void kernel_launch(void* const* d_in, const int* in_sizes, int n_in,
                              void* d_out, int out_size, void* d_ws, size_t ws_size,
                              hipStream_t stream)
{
    const float* x  = (const float*)d_in[0];
    const float* Wq = (const float*)d_in[1];
    const float* bq = (const float*)d_in[2];
    const float* Wk = (const float*)d_in[3];
    const float* bk = (const float*)d_in[4];
    const float* Wv = (const float*)d_in[5];
    const float* bv = (const float*)d_in[6];
    const float* gm = (const float*)d_in[7];
    float* out = (float*)d_out;
    float* ws  = (float*)d_ws;

    float* scale = ws;                       // [0..3]
    float* kmax  = ws + 4;                   // [4..7]
    float* qnorm = ws + 8;                   // NB*N_SP
    u8* Wqb = (u8*)(ws + 8 + NB * N_SP);     // 16B-aligned
    u8* Wkb = Wqb + 32 * 512;
    u8* Wvb = Wkb + 32 * 512;
    u8* xT  = Wvb + 256 * 512;
    u16* qT = (u16*)(xT + (size_t)NB * N_SP * 512);
    u8* Kg  = (u8*)(qT + (size_t)NB * N_SP * CQ);
    u8* Vg  = Kg + (size_t)NB * N_SP * 64;

    stage1_kernel<<<865, 256, 0, stream>>>(x, Wq, Wk, Wv, xT, Wqb, Wkb, Wvb, scale, kmax);
    qkv_mfma<<<984, 256, 0, stream>>>(xT, Wqb, Wkb, Wvb, bq, bk, bv, scale, qT, Kg, Vg, qnorm, kmax);
    attn_mfma<<<196, 1024, 0, stream>>>(qT, Kg, Vg, x, gm, qnorm, kmax, out);
}

// Round 19
// 82.312 us; speedup vs baseline: 1.1311x; 1.0396x over previous
//
#include <hip/hip_runtime.h>

#define N_SP 3136   // H*W = 49*64
#define C_CH 256
#define CQ   32
#define NB   4
#define JT   64     // attn j-tile
#define NJT  49     // j-tiles (exact)
#define QT   64     // attn q-tile (49 tiles exact)
// 1 / (exp(sqrt(3))*sqrt(3136/256) + 2*sqrt(6))
#define INV_BOUND 0.04051569f
#define LOG2E 1.44269504f

typedef __attribute__((ext_vector_type(8))) short bf16x8;
typedef __attribute__((ext_vector_type(4))) float f32x4;
typedef __attribute__((ext_vector_type(2))) long long l64x2;
typedef unsigned short u16;
typedef unsigned int   u32;
typedef unsigned char  u8;
typedef long long      l64;

#define MFMA16(a,b,c) __builtin_amdgcn_mfma_f32_16x16x32_bf16(a,b,c,0,0,0)
#define MFMA8(a,b,c)  __builtin_amdgcn_mfma_f32_16x16x32_bf8_fp8(a,b,c,0,0,0)

__device__ __forceinline__ u16 f2b(float f) {
    u32 u = __builtin_bit_cast(u32, f);
    u += 0x7fffu + ((u >> 16) & 1u);   // RTNE
    return (u16)(u >> 16);
}
__device__ __forceinline__ u8 f2fp8(float f) {
    return (u8)(__builtin_amdgcn_cvt_pk_fp8_f32(f, f, 0, false) & 0xff);
}
__device__ __forceinline__ void dma16(const void* g, void* l) {
    __builtin_amdgcn_global_load_lds((const __attribute__((address_space(1))) u32*)g,
                                     (__attribute__((address_space(3))) u32*)l, 16, 0, 0);
}

// ---------------------------------------------------------------------------
// stage1 (verified): xT transpose pre-swizzled, W->bf16 pre-swizzled,
// norm+scale+kmax0.
// ---------------------------------------------------------------------------
__global__ __launch_bounds__(256) void stage1_kernel(
    const float* __restrict__ x, const float* __restrict__ Wq,
    const float* __restrict__ Wk, const float* __restrict__ Wv,
    u8* __restrict__ xT, u8* __restrict__ Wqb, u8* __restrict__ Wkb,
    u8* __restrict__ Wvb, float* __restrict__ scale_out,
    float* __restrict__ kmax)
{
    __shared__ float smem[64 * 65];
    const int t = threadIdx.x;
    const int bid = blockIdx.x;

    if (bid < 784) {
        float (*tile)[65] = (float(*)[65])smem;
        const int xcd = bid & 7, slot = bid >> 3;
        const int b = xcd >> 1;
        const int i = slot * 2 + (xcd & 1);          // 0..195
        const int ct = i & 3, nt = i >> 2;           // 4 x 49
        const int c0 = ct * 64, n0 = nt * 64;
        const int cc = t >> 4, nn4 = (t & 15) * 4;
        #pragma unroll
        for (int k = 0; k < 4; ++k) {
            int cl = cc + k * 16;
            float4 v = *(const float4*)(x + (size_t)(b * C_CH + c0 + cl) * N_SP + n0 + nn4);
            tile[cl][nn4] = v.x; tile[cl][nn4 + 1] = v.y;
            tile[cl][nn4 + 2] = v.z; tile[cl][nn4 + 3] = v.w;
        }
        __syncthreads();
        const int c4 = (t & 15) * 4, nn = t >> 4;
        #pragma unroll
        for (int k = 0; k < 4; ++k) {
            int nl = nn + k * 16;
            ushort4 o;
            o.x = f2b(tile[c4 + 0][nl]); o.y = f2b(tile[c4 + 1][nl]);
            o.z = f2b(tile[c4 + 2][nl]); o.w = f2b(tile[c4 + 3][nl]);
            const int off = ((c0 + c4) * 2) ^ ((nl & 15) << 5);
            *(ushort4*)(xT + (size_t)(b * N_SP + n0 + nl) * 512 + off) = o;
        }
    } else if (bid < 864) {
        int idx = (bid - 784) * 256 + t;
        const float* src; u8* dst; int off;
        if (idx < 2048)      { src = Wq; dst = Wqb; off = idx; }
        else if (idx < 4096) { src = Wk; dst = Wkb; off = idx - 2048; }
        else                 { src = Wv; dst = Wvb; off = idx - 4096; }
        float4 v = *(const float4*)(src + off * 4);
        ushort4 o; o.x = f2b(v.x); o.y = f2b(v.y); o.z = f2b(v.z); o.w = f2b(v.w);
        const int row = off >> 6, inner = (off & 63) * 8;
        *(ushort4*)(dst + row * 512 + (inner ^ ((row & 15) << 5))) = o;
    } else {
        if (t < NB) kmax[t] = 0.f;
        float* red = smem;
        float u2 = 0.f;
        for (int i = t; i < CQ * C_CH; i += 256) { float w = Wq[i]; u2 += w * w; }
        red[t] = u2; __syncthreads();
        #pragma unroll
        for (int s = 128; s > 0; s >>= 1) { if (t < s) red[t] += red[t + s]; __syncthreads(); }
        float u2t = red[0]; __syncthreads();
        float vn2 = 0.f;
        for (int o = 0; o < CQ; ++o)   { float w = Wk[o * C_CH + t]; vn2 += w * w; }
        float wn2 = 0.f;
        for (int o = 0; o < C_CH; ++o) { float w = Wv[o * C_CH + t]; wn2 += w * w; }
        red[t] = fmaxf(vn2, wn2); __syncthreads();
        #pragma unroll
        for (int s = 128; s > 0; s >>= 1) { if (t < s) red[t] = fmaxf(red[t], red[t + s]); __syncthreads(); }
        if (t == 0) scale_out[0] = 1.0f / (sqrtf(u2t) * sqrtf(red[0]));
    }
}

// ---------------------------------------------------------------------------
// qkv (verified): XCD-affine grid 984; DMA-staged x/W -> LDS -> MFMA.
// ---------------------------------------------------------------------------
__global__ __launch_bounds__(256) void qkv_mfma(
    const u8* __restrict__ xT, const u8* __restrict__ Wqb,
    const u8* __restrict__ Wkb, const u8* __restrict__ Wvb,
    const float* __restrict__ bq, const float* __restrict__ bk,
    const float* __restrict__ bv, const float* __restrict__ scale_p,
    u16* __restrict__ qT, u8* __restrict__ Kg, u8* __restrict__ Vg,
    float* __restrict__ qnorm, float* __restrict__ kmax)
{
    __shared__ __align__(16) u8 xTl[32768];
    __shared__ __align__(16) u8 Wl[32768];

    const int t = threadIdx.x;
    const int xcd = blockIdx.x & 7, slot = blockIdx.x >> 3;
    const int b = xcd >> 1;
    const int i = slot * 2 + (xcd & 1);
    if (i >= 245) return;
    const int split = i / 49, nt = i % 49;
    const int w = t >> 6, lane = t & 63, li = t & 15, g = (t >> 4) & 3;
    const int n = nt * 64 + w * 16 + li;
    const int r0 = (split - 1) * 64;
    const f32x4 zero = {0.f, 0.f, 0.f, 0.f};

    {
        const u8* xsrc = xT + (size_t)(b * N_SP + nt * 64) * 512;
        #pragma unroll
        for (int k = 0; k < 8; ++k)
            dma16(xsrc + w * 8192 + k * 1024 + lane * 16, xTl + w * 8192 + k * 1024);
        if (split == 0) {
            #pragma unroll
            for (int k = 0; k < 4; ++k)
                dma16(Wqb + w * 4096 + k * 1024 + lane * 16, Wl + w * 4096 + k * 1024);
            #pragma unroll
            for (int k = 0; k < 4; ++k)
                dma16(Wkb + w * 4096 + k * 1024 + lane * 16, Wl + 16384 + w * 4096 + k * 1024);
        } else {
            const u8* wsrc = Wvb + (size_t)r0 * 512;
            #pragma unroll
            for (int k = 0; k < 8; ++k)
                dma16(wsrc + w * 8192 + k * 1024 + lane * 16, Wl + w * 8192 + k * 1024);
        }
    }
    asm volatile("s_waitcnt vmcnt(0)" ::: "memory");
    __syncthreads();

    const int swz = li << 5;
    bf16x8 xf[8];
    #pragma unroll
    for (int ks = 0; ks < 8; ++ks)
        xf[ks] = *(const bf16x8*)(xTl + (w * 16 + li) * 512 + ((ks * 64 + 16 * g) ^ swz));

    if (split == 0) {
        f32x4 aq0 = zero, aq1 = zero, ak0 = zero, ak1 = zero;
        #pragma unroll
        for (int ks = 0; ks < 8; ++ks) {
            const int o = (ks * 64 + 16 * g) ^ swz;
            bf16x8 w0 = *(const bf16x8*)(Wl + li * 512 + o);
            bf16x8 w1 = *(const bf16x8*)(Wl + (16 + li) * 512 + o);
            bf16x8 w2 = *(const bf16x8*)(Wl + 16384 + li * 512 + o);
            bf16x8 w3 = *(const bf16x8*)(Wl + 16384 + (16 + li) * 512 + o);
            aq0 = MFMA16(w0, xf[ks], aq0);
            aq1 = MFMA16(w1, xf[ks], aq1);
            ak0 = MFMA16(w2, xf[ks], ak0);
            ak1 = MFMA16(w3, xf[ks], ak1);
        }
        const float scf = scale_p[0] * LOG2E;
        f32x4 bq0 = *(const f32x4*)(bq + 4 * g);
        f32x4 bq1 = *(const f32x4*)(bq + 16 + 4 * g);
        f32x4 bk0 = *(const f32x4*)(bk + 4 * g);
        f32x4 bk1 = *(const f32x4*)(bk + 16 + 4 * g);
        float qn2 = 0.f, kn2 = 0.f;
        ushort4 s0, s1;
        #pragma unroll
        for (int r = 0; r < 4; ++r) {
            float q0 = (aq0[r] + bq0[r]) * scf;
            float q1 = (aq1[r] + bq1[r]) * scf;
            qn2 += q0 * q0 + q1 * q1;
            ((u16*)&s0)[r] = f2b(q0); ((u16*)&s1)[r] = f2b(q1);
        }
        *(ushort4*)(qT + (size_t)(b * N_SP + n) * CQ + 4 * g)      = s0;
        *(ushort4*)(qT + (size_t)(b * N_SP + n) * CQ + 16 + 4 * g) = s1;
        #pragma unroll
        for (int r = 0; r < 4; ++r) {
            float k0 = ak0[r] + bk0[r];
            float k1 = ak1[r] + bk1[r];
            kn2 += k0 * k0 + k1 * k1;
            ((u16*)&s0)[r] = f2b(k0); ((u16*)&s1)[r] = f2b(k1);
        }
        u8* krow = Kg + ((size_t)b * N_SP + n) * 64;
        const int swn = ((n >> 1) & 3) << 4;
        *(ushort4*)(krow + ((8 * g) ^ swn))      = s0;
        *(ushort4*)(krow + ((32 + 8 * g) ^ swn)) = s1;

        qn2 += __shfl_xor(qn2, 16); qn2 += __shfl_xor(qn2, 32);
        kn2 += __shfl_xor(kn2, 16); kn2 += __shfl_xor(kn2, 32);
        if (g == 0) qnorm[b * N_SP + n] = sqrtf(qn2);
        float kn = sqrtf(kn2);
        #pragma unroll
        for (int d = 1; d < 16; d <<= 1) kn = fmaxf(kn, __shfl_xor(kn, d));
        if ((t & 63) == 0) atomicMax((int*)(kmax + b), __float_as_int(kn));
    } else {
        f32x4 a[4] = {zero, zero, zero, zero};
        #pragma unroll
        for (int ks = 0; ks < 8; ++ks) {
            const int o = (ks * 64 + 16 * g) ^ swz;
            #pragma unroll
            for (int fr = 0; fr < 4; ++fr) {
                bf16x8 wf = *(const bf16x8*)(Wl + (fr * 16 + li) * 512 + o);
                a[fr] = MFMA16(wf, xf[ks], a[fr]);
            }
        }
        const int jj = w * 16 + li;
        const int p = ((jj >> 5) & 1) * 8 + ((jj >> 3) & 3) * 16 + (jj & 7);
        u8* vtile = Vg + (size_t)(b * NJT + nt) * 16384;
        #pragma unroll
        for (int fr = 0; fr < 4; ++fr) {
            f32x4 bb = *(const f32x4*)(bv + r0 + fr * 16 + 4 * g);
            #pragma unroll
            for (int r = 0; r < 4; ++r) {
                const int c = r0 + fr * 16 + 4 * g + r;
                vtile[c * 64 + (p ^ (((c >> 1) & 3) << 4))] = f2fp8(a[fr][r] + bb[r]);
            }
        }
    }
}

// ---------------------------------------------------------------------------
// Attention: 196 blocks x 1024 thr (16 waves), ONE barrier per j-tile.
// Software pipeline: in barrier region of iter `it`, PV(it-1) and S(it) run
// together (P double-buffered). Ring-4 V/K, depth-2 DMA (slot (it+2)&3 whose
// previous reader drained at iter it-1 => race-free). Counted per-wave vmcnt.
// ---------------------------------------------------------------------------
__global__ __launch_bounds__(1024) void attn_mfma(
    const u16* __restrict__ qT, const u8* __restrict__ Kg,
    const u8* __restrict__ Vg, const float* __restrict__ x,
    const float* __restrict__ gamma_p, const float* __restrict__ qnorm,
    const float* __restrict__ kmax, float* __restrict__ out)
{
    __shared__ __align__(16) u8 smem[90112];
    u8* const Vl = smem;             // 4 x 16384
    u8* const Kl = smem + 65536;     // 4 x 4096
    u8* const Pl = smem + 81920;     // 2 x 4096 dbuf (reduce overlays after)

    const int t = threadIdx.x;
    const int w = t >> 6, li = t & 15, g = (t >> 4) & 3;
    const int jh = w & 3, qh = w >> 2;               // qh 0..3, jh 0..3
    const int swz = ((li >> 1) & 3) << 4;

    const int b  = blockIdx.x / NJT;
    const int qt = blockIdx.x % NJT;
    const int i0 = qt * QT;

    const u16* qTb = qT + (size_t)b * N_SP * CQ;
    const u8*  Kbb = Kg + (size_t)b * N_SP * 64;
    const u8*  Vbb = Vg + (size_t)b * NJT * 16384;
    const float kmb = kmax[b];
    const f32x4 zero = {0.f, 0.f, 0.f, 0.f};

    const bf16x8 qf = *(const bf16x8*)(qTb + (size_t)(i0 + qh * 16 + li) * CQ + 8 * g);
    const float  mr = qnorm[b * N_SP + i0 + qh * 16 + li] * kmb;

    f32x4 acc[4];
    #pragma unroll
    for (int qq = 0; qq < 4; ++qq) acc[qq] = zero;
    float ls = 0.f;

    #define ISSUE(jt_, s_) do {                                               \
        dma16(Vbb + (size_t)(jt_) * 16384 + t * 16,                           \
              Vl + (s_) * 16384 + w * 1024);                                  \
        if (t < 256)                                                          \
            dma16(Kbb + (size_t)(jt_) * 4096 + t * 16,                        \
                  Kl + (s_) * 4096 + w * 1024);                               \
    } while (0)

    // S-phase for tile it_: K slot it_&3, P buffer it_&1
    #define SPHASE(it_) do {                                                  \
        const u8* Kc_ = Kl + ((it_) & 3) * 4096;                              \
        bf16x8 kf_ = *(const bf16x8*)(Kc_ + (jh * 16 + li) * 64 + ((16 * g) ^ swz)); \
        f32x4 s_ = MFMA16(kf_, qf, zero);                                     \
        float a0_ = exp2f(s_[0] - mr), a1_ = exp2f(s_[1] - mr);               \
        float a2_ = exp2f(s_[2] - mr), a3_ = exp2f(s_[3] - mr);               \
        ls += (a0_ + a1_) + (a2_ + a3_);                                      \
        int pk_ = __builtin_amdgcn_cvt_pk_bf8_f32(a0_, a1_, 0, false);        \
        pk_ = __builtin_amdgcn_cvt_pk_bf8_f32(a2_, a3_, pk_, true);           \
        *(u32*)(Pl + ((it_) & 1) * 4096 + (qh * 16 + li) * 64 + (p0 ^ swz)) = (u32)pk_; \
    } while (0)

    // PV-phase for tile it_: P buffer it_&1, V slot it_&3
    #define PVPHASE(it_) do {                                                 \
        const u8* Pp_ = Pl + ((it_) & 1) * 4096;                              \
        const u8* Vc_ = Vl + ((it_) & 3) * 16384;                             \
        __builtin_amdgcn_s_setprio(1);                                        \
        l64x2 pa0_ = *(const l64x2*)(Pp_ + (0 * 16 + li) * 64 + ((16 * g) ^ swz)); \
        l64x2 pa1_ = *(const l64x2*)(Pp_ + (1 * 16 + li) * 64 + ((16 * g) ^ swz)); \
        l64x2 pa2_ = *(const l64x2*)(Pp_ + (2 * 16 + li) * 64 + ((16 * g) ^ swz)); \
        l64x2 pa3_ = *(const l64x2*)(Pp_ + (3 * 16 + li) * 64 + ((16 * g) ^ swz)); \
        l64x2 v0_  = *(const l64x2*)(Vc_ + (w * 16 + li) * 64 + ((16 * g) ^ swz)); \
        acc[0] = MFMA8(pa0_[0], v0_[0], acc[0]);                              \
        acc[1] = MFMA8(pa1_[0], v0_[0], acc[1]);                              \
        acc[2] = MFMA8(pa2_[0], v0_[0], acc[2]);                              \
        acc[3] = MFMA8(pa3_[0], v0_[0], acc[3]);                              \
        acc[0] = MFMA8(pa0_[1], v0_[1], acc[0]);                              \
        acc[1] = MFMA8(pa1_[1], v0_[1], acc[1]);                              \
        acc[2] = MFMA8(pa2_[1], v0_[1], acc[2]);                              \
        acc[3] = MFMA8(pa3_[1], v0_[1], acc[3]);                              \
        __builtin_amdgcn_s_setprio(0);                                        \
    } while (0)

    ISSUE(0, 0);
    ISSUE(1, 1);

    // P write byte position: j' = jh*16 + 4g (+r)
    const int p0 = ((jh >> 1) & 1) * 8 + ((jh * 2 + (g >> 1)) & 3) * 16 + 4 * (g & 1);

    // ---- peeled iter 0: S only ----
    if (w < 4) asm volatile("s_waitcnt vmcnt(2) lgkmcnt(0)" ::: "memory");
    else       asm volatile("s_waitcnt vmcnt(1) lgkmcnt(0)" ::: "memory");
    __builtin_amdgcn_s_barrier();
    asm volatile("" ::: "memory");
    ISSUE(2, 2);
    SPHASE(0);

    // ---- main loop: iter it does PV(it-1) + S(it) in ONE barrier region ----
    for (int it = 1; it < NJT; ++it) {
        if (w < 4) asm volatile("s_waitcnt vmcnt(2) lgkmcnt(0)" ::: "memory");
        else       asm volatile("s_waitcnt vmcnt(1) lgkmcnt(0)" ::: "memory");
        __builtin_amdgcn_s_barrier();
        asm volatile("" ::: "memory");
        {
            int jn = it + 2; if (jn > NJT - 1) jn = NJT - 1;
            ISSUE(jn, (it + 2) & 3);
        }
        PVPHASE(it - 1);
        SPHASE(it);
    }

    // ---- tail: PV(NJT-1) ----
    asm volatile("s_waitcnt lgkmcnt(0)" ::: "memory");
    __builtin_amdgcn_s_barrier();
    asm volatile("" ::: "memory");
    PVPHASE(NJT - 1);
    #undef ISSUE
    #undef SPHASE
    #undef PVPHASE

    // ---- denominators (reduce buffers overlay P region) ----
    ls += __shfl_xor(ls, 16); ls += __shfl_xor(ls, 32);
    __syncthreads();
    float* red       = (float*)Pl;           // [16 waves][16 q]
    float* red_final = (float*)(Pl + 1024);  // [64 q]
    if ((t & 63) < 16) red[w * 16 + li] = ls;
    __syncthreads();
    if (t < 64) {
        const int qh2 = t >> 4, l2 = t & 15;
        float s = red[(qh2 * 4 + 0) * 16 + l2] + red[(qh2 * 4 + 1) * 16 + l2]
                + red[(qh2 * 4 + 2) * 16 + l2] + red[(qh2 * 4 + 3) * 16 + l2];
        red_final[t] = s;
    }
    __syncthreads();

    // ---- epilogue: wave w -> channels w*16..w*16+15, 4 q-frags ----
    const float gsc = gamma_p[0] * INV_BOUND;
    const int c = w * 16 + li;
    #pragma unroll
    for (int qq = 0; qq < 4; ++qq) {
        f32x4 lsv = *(const f32x4*)(red_final + qq * 16 + 4 * g);
        f32x4 rinv;
        #pragma unroll
        for (int r = 0; r < 4; ++r) rinv[r] = gsc / lsv[r];
        const size_t base = ((size_t)b * C_CH + c) * N_SP + i0 + qq * 16 + 4 * g;
        float4 xv = *(const float4*)(x + base);
        float4 o;
        o.x = acc[qq][0] * rinv[0] + xv.x;
        o.y = acc[qq][1] * rinv[1] + xv.y;
        o.z = acc[qq][2] * rinv[2] + xv.z;
        o.w = acc[qq][3] * rinv[3] + xv.w;
        *(float4*)(out + base) = o;
    }
}

// ---------------------------------------------------------------------------
extern "C" void kernel_launch(void* const* d_in, const int* in_sizes, int n_in,
                              void* d_out, int out_size, void* d_ws, size_t ws_size,
                              hipStream_t stream)
{
    const float* x  = (const float*)d_in[0];
    const float* Wq = (const float*)d_in[1];
    const float* bq = (const float*)d_in[2];
    const float* Wk = (const float*)d_in[3];
    const float* bk = (const float*)d_in[4];
    const float* Wv = (const float*)d_in[5];
    const float* bv = (const float*)d_in[6];
    const float* gm = (const float*)d_in[7];
    float* out = (float*)d_out;
    float* ws  = (float*)d_ws;

    float* scale = ws;                       // [0..3]
    float* kmax  = ws + 4;                   // [4..7]
    float* qnorm = ws + 8;                   // NB*N_SP
    u8* Wqb = (u8*)(ws + 8 + NB * N_SP);     // 16B-aligned
    u8* Wkb = Wqb + 32 * 512;
    u8* Wvb = Wkb + 32 * 512;
    u8* xT  = Wvb + 256 * 512;
    u16* qT = (u16*)(xT + (size_t)NB * N_SP * 512);
    u8* Kg  = (u8*)(qT + (size_t)NB * N_SP * CQ);
    u8* Vg  = Kg + (size_t)NB * N_SP * 64;

    stage1_kernel<<<865, 256, 0, stream>>>(x, Wq, Wk, Wv, xT, Wqb, Wkb, Wvb, scale, kmax);
    qkv_mfma<<<984, 256, 0, stream>>>(xT, Wqb, Wkb, Wvb, bq, bk, bv, scale, qT, Kg, Vg, qnorm, kmax);
    attn_mfma<<<196, 1024, 0, stream>>>(qT, Kg, Vg, x, gm, qnorm, kmax, out);
}

// Round 20
// 81.319 us; speedup vs baseline: 1.1449x; 1.0122x over previous
//
#include <hip/hip_runtime.h>

#define N_SP 3136   // H*W = 49*64
#define C_CH 256
#define CQ   32
#define NB   4
#define JT   64     // attn j-tile
#define NJT  49     // j-tiles (exact)
#define QT   64     // attn q-tile (49 tiles exact)
// 1 / (exp(sqrt(3))*sqrt(3136/256) + 2*sqrt(6))
#define INV_BOUND 0.04051569f
#define LOG2E 1.44269504f

typedef __attribute__((ext_vector_type(8))) short bf16x8;
typedef __attribute__((ext_vector_type(4))) float f32x4;
typedef __attribute__((ext_vector_type(2))) long long l64x2;
typedef unsigned short u16;
typedef unsigned int   u32;
typedef unsigned char  u8;
typedef long long      l64;

#define MFMA16(a,b,c) __builtin_amdgcn_mfma_f32_16x16x32_bf16(a,b,c,0,0,0)
#define MFMA8(a,b,c)  __builtin_amdgcn_mfma_f32_16x16x32_bf8_fp8(a,b,c,0,0,0)

__device__ __forceinline__ u16 f2b(float f) {
    u32 u = __builtin_bit_cast(u32, f);
    u += 0x7fffu + ((u >> 16) & 1u);   // RTNE
    return (u16)(u >> 16);
}
__device__ __forceinline__ u8 f2fp8(float f) {
    return (u8)(__builtin_amdgcn_cvt_pk_fp8_f32(f, f, 0, false) & 0xff);
}
__device__ __forceinline__ void dma16(const void* g, void* l) {
    __builtin_amdgcn_global_load_lds((const __attribute__((address_space(1))) u32*)g,
                                     (__attribute__((address_space(3))) u32*)l, 16, 0, 0);
}

// ---------------------------------------------------------------------------
// stage0: W->bf16 pre-swizzled (blocks 0..79), norm+scale+kmax0 (block 80)
// ---------------------------------------------------------------------------
__global__ __launch_bounds__(256) void stage0_kernel(
    const float* __restrict__ Wq, const float* __restrict__ Wk,
    const float* __restrict__ Wv, u8* __restrict__ Wqb,
    u8* __restrict__ Wkb, u8* __restrict__ Wvb,
    float* __restrict__ scale_out, float* __restrict__ kmax)
{
    __shared__ float red[256];
    const int t = threadIdx.x;
    const int bid = blockIdx.x;

    if (bid < 80) {
        int idx = bid * 256 + t;
        const float* src; u8* dst; int off;
        if (idx < 2048)      { src = Wq; dst = Wqb; off = idx; }
        else if (idx < 4096) { src = Wk; dst = Wkb; off = idx - 2048; }
        else                 { src = Wv; dst = Wvb; off = idx - 4096; }
        float4 v = *(const float4*)(src + off * 4);
        ushort4 o; o.x = f2b(v.x); o.y = f2b(v.y); o.z = f2b(v.z); o.w = f2b(v.w);
        const int row = off >> 6, inner = (off & 63) * 8;
        *(ushort4*)(dst + row * 512 + (inner ^ ((row & 15) << 5))) = o;
    } else {
        if (t < NB) kmax[t] = 0.f;
        float u2 = 0.f;
        for (int i = t; i < CQ * C_CH; i += 256) { float w = Wq[i]; u2 += w * w; }
        red[t] = u2; __syncthreads();
        #pragma unroll
        for (int s = 128; s > 0; s >>= 1) { if (t < s) red[t] += red[t + s]; __syncthreads(); }
        float u2t = red[0]; __syncthreads();
        float vn2 = 0.f;
        for (int o = 0; o < CQ; ++o)   { float w = Wk[o * C_CH + t]; vn2 += w * w; }
        float wn2 = 0.f;
        for (int o = 0; o < C_CH; ++o) { float w = Wv[o * C_CH + t]; wn2 += w * w; }
        red[t] = fmaxf(vn2, wn2); __syncthreads();
        #pragma unroll
        for (int s = 128; s > 0; s >>= 1) { if (t < s) red[t] = fmaxf(red[t], red[t + s]); __syncthreads(); }
        if (t == 0) scale_out[0] = 1.0f / (sqrtf(u2t) * sqrtf(red[0]));
    }
}

// ---------------------------------------------------------------------------
// qkv_fused: 196 blocks (b, nt) x 512 thr. Per block:
//  Phase A: transpose x-tile [256c][64n] f32 -> bf16 swizzled xTl (4 slabs
//           via banked f32 staging tile) -- x read ONCE, no xT global buffer.
//  W streamed by DMA: W0 = Wq|Wk (32K, issued at start), W1 = Wv half (64K,
//  issued at start; re-DMA'd for second half after a barrier).
//  Sections (512 thr, wh = w>>2): A: wh0=q, wh1=k (+qnorm/kmax);
//  B: V rows 0..127; C: V rows 128..255. Compute bodies = verified R12 code.
// ---------------------------------------------------------------------------
__global__ __launch_bounds__(512) void qkv_fused(
    const float* __restrict__ x, const u8* __restrict__ Wqb,
    const u8* __restrict__ Wkb, const u8* __restrict__ Wvb,
    const float* __restrict__ bq, const float* __restrict__ bk,
    const float* __restrict__ bv, const float* __restrict__ scale_p,
    u16* __restrict__ qT, u8* __restrict__ Kg, u8* __restrict__ Vg,
    float* __restrict__ qnorm, float* __restrict__ kmax)
{
    __shared__ __align__(16) u8 smem[147712];
    u8* const xTl = smem;                    // 32768: [64n][512B] swizzled bf16
    float* const ftile = (float*)(smem + 32768);   // [64][65] f32 staging
    u8* const W0 = smem + 49408;             // 32768: Wq|Wk
    u8* const W1 = smem + 82176;             // 65536: Wv half

    const int t = threadIdx.x;
    const int w = t >> 6, lane = t & 63, li = t & 15, g = (t >> 4) & 3;
    const int wq = w & 3, wh = w >> 2;
    const int b  = blockIdx.x / NJT;
    const int nt = blockIdx.x % NJT;
    const int n0 = nt * 64;
    const f32x4 zero = {0.f, 0.f, 0.f, 0.f};

    // ---- issue W DMAs up front ----
    #pragma unroll
    for (int k = 0; k < 2; ++k)
        dma16(Wqb + k * 8192 + t * 16, W0 + k * 8192 + w * 1024);
    #pragma unroll
    for (int k = 0; k < 2; ++k)
        dma16(Wkb + k * 8192 + t * 16, W0 + 16384 + k * 8192 + w * 1024);
    #pragma unroll
    for (int k = 0; k < 8; ++k)
        dma16(Wvb + k * 8192 + t * 16, W1 + k * 8192 + w * 1024);

    // ---- Phase A: transpose 4 slabs of [64c][64n] ----
    #pragma unroll 1
    for (int sl = 0; sl < 4; ++sl) {
        const int c0 = sl * 64;
        if (t < 256) {
            const int cc = t >> 4, nn4 = (t & 15) * 4;
            #pragma unroll
            for (int k = 0; k < 4; ++k) {
                int cl = cc + k * 16;
                float4 v = *(const float4*)(x + (size_t)(b * C_CH + c0 + cl) * N_SP + n0 + nn4);
                ftile[cl * 65 + nn4]     = v.x;
                ftile[cl * 65 + nn4 + 1] = v.y;
                ftile[cl * 65 + nn4 + 2] = v.z;
                ftile[cl * 65 + nn4 + 3] = v.w;
            }
        }
        __syncthreads();
        if (t < 256) {
            const int c4 = (t & 15) * 4, nn = t >> 4;
            #pragma unroll
            for (int k = 0; k < 4; ++k) {
                int nl = nn + k * 16;
                ushort4 o;
                o.x = f2b(ftile[(c4 + 0) * 65 + nl]);
                o.y = f2b(ftile[(c4 + 1) * 65 + nl]);
                o.z = f2b(ftile[(c4 + 2) * 65 + nl]);
                o.w = f2b(ftile[(c4 + 3) * 65 + nl]);
                *(ushort4*)(xTl + nl * 512 + (((c0 + c4) * 2) ^ ((nl & 15) << 5))) = o;
            }
        }
        __syncthreads();
    }

    // ---- drain W DMAs; load x fragments ----
    asm volatile("s_waitcnt vmcnt(0) lgkmcnt(0)" ::: "memory");
    __syncthreads();

    const int swz = li << 5;
    const int n = n0 + wq * 16 + li;
    bf16x8 xf[8];
    #pragma unroll
    for (int ks = 0; ks < 8; ++ks)
        xf[ks] = *(const bf16x8*)(xTl + (wq * 16 + li) * 512 + ((ks * 64 + 16 * g) ^ swz));

    // ---- Section A: wh==0 -> q (+qnorm), wh==1 -> k (+kmax) ----
    if (wh == 0) {
        f32x4 aq0 = zero, aq1 = zero;
        #pragma unroll
        for (int ks = 0; ks < 8; ++ks) {
            const int o = (ks * 64 + 16 * g) ^ swz;
            bf16x8 w0 = *(const bf16x8*)(W0 + li * 512 + o);
            bf16x8 w1 = *(const bf16x8*)(W0 + (16 + li) * 512 + o);
            aq0 = MFMA16(w0, xf[ks], aq0);
            aq1 = MFMA16(w1, xf[ks], aq1);
        }
        const float scf = scale_p[0] * LOG2E;
        f32x4 bq0 = *(const f32x4*)(bq + 4 * g);
        f32x4 bq1 = *(const f32x4*)(bq + 16 + 4 * g);
        float qn2 = 0.f;
        ushort4 s0, s1;
        #pragma unroll
        for (int r = 0; r < 4; ++r) {
            float q0 = (aq0[r] + bq0[r]) * scf;
            float q1 = (aq1[r] + bq1[r]) * scf;
            qn2 += q0 * q0 + q1 * q1;
            ((u16*)&s0)[r] = f2b(q0); ((u16*)&s1)[r] = f2b(q1);
        }
        *(ushort4*)(qT + (size_t)(b * N_SP + n) * CQ + 4 * g)      = s0;
        *(ushort4*)(qT + (size_t)(b * N_SP + n) * CQ + 16 + 4 * g) = s1;
        qn2 += __shfl_xor(qn2, 16); qn2 += __shfl_xor(qn2, 32);
        if (g == 0) qnorm[b * N_SP + n] = sqrtf(qn2);
    } else {
        f32x4 ak0 = zero, ak1 = zero;
        #pragma unroll
        for (int ks = 0; ks < 8; ++ks) {
            const int o = (ks * 64 + 16 * g) ^ swz;
            bf16x8 w2 = *(const bf16x8*)(W0 + 16384 + li * 512 + o);
            bf16x8 w3 = *(const bf16x8*)(W0 + 16384 + (16 + li) * 512 + o);
            ak0 = MFMA16(w2, xf[ks], ak0);
            ak1 = MFMA16(w3, xf[ks], ak1);
        }
        f32x4 bk0 = *(const f32x4*)(bk + 4 * g);
        f32x4 bk1 = *(const f32x4*)(bk + 16 + 4 * g);
        float kn2 = 0.f;
        ushort4 s0, s1;
        #pragma unroll
        for (int r = 0; r < 4; ++r) {
            float k0 = ak0[r] + bk0[r];
            float k1 = ak1[r] + bk1[r];
            kn2 += k0 * k0 + k1 * k1;
            ((u16*)&s0)[r] = f2b(k0); ((u16*)&s1)[r] = f2b(k1);
        }
        u8* krow = Kg + ((size_t)b * N_SP + n) * 64;
        const int swn = ((n >> 1) & 3) << 4;
        *(ushort4*)(krow + ((8 * g) ^ swn))      = s0;
        *(ushort4*)(krow + ((32 + 8 * g) ^ swn)) = s1;
        kn2 += __shfl_xor(kn2, 16); kn2 += __shfl_xor(kn2, 32);
        float kn = sqrtf(kn2);
        #pragma unroll
        for (int d = 1; d < 16; d <<= 1) kn = fmaxf(kn, __shfl_xor(kn, d));
        if (lane == 0) atomicMax((int*)(kmax + b), __float_as_int(kn));
    }

    // ---- Section B: V rows wh*64 .. wh*64+63 (from W1 = Wv[0:128]) ----
    const int jj = wq * 16 + li;
    const int p = ((jj >> 5) & 1) * 8 + ((jj >> 3) & 3) * 16 + (jj & 7);
    u8* vtile = Vg + (size_t)(b * NJT + nt) * 16384;
    {
        const int r0 = wh * 64;
        f32x4 a[4] = {zero, zero, zero, zero};
        #pragma unroll
        for (int ks = 0; ks < 8; ++ks) {
            const int o = (ks * 64 + 16 * g) ^ swz;
            #pragma unroll
            for (int fr = 0; fr < 4; ++fr) {
                bf16x8 wf = *(const bf16x8*)(W1 + (size_t)(r0 + fr * 16 + li) * 512 + o);
                a[fr] = MFMA16(wf, xf[ks], a[fr]);
            }
        }
        #pragma unroll
        for (int fr = 0; fr < 4; ++fr) {
            f32x4 bb = *(const f32x4*)(bv + r0 + fr * 16 + 4 * g);
            #pragma unroll
            for (int r = 0; r < 4; ++r) {
                const int c = r0 + fr * 16 + 4 * g + r;
                vtile[c * 64 + (p ^ (((c >> 1) & 3) << 4))] = f2fp8(a[fr][r] + bb[r]);
            }
        }
    }

    // ---- swap W1 to Wv[128:256] ----
    __syncthreads();
    #pragma unroll
    for (int k = 0; k < 8; ++k)
        dma16(Wvb + 65536 + k * 8192 + t * 16, W1 + k * 8192 + w * 1024);
    asm volatile("s_waitcnt vmcnt(0)" ::: "memory");
    __syncthreads();

    // ---- Section C: V rows 128 + wh*64 .. +63 ----
    {
        const int r0v = 128 + wh * 64;       // global V row base
        const int r0l = wh * 64;             // row base within W1
        f32x4 a[4] = {zero, zero, zero, zero};
        #pragma unroll
        for (int ks = 0; ks < 8; ++ks) {
            const int o = (ks * 64 + 16 * g) ^ swz;
            #pragma unroll
            for (int fr = 0; fr < 4; ++fr) {
                bf16x8 wf = *(const bf16x8*)(W1 + (size_t)(r0l + fr * 16 + li) * 512 + o);
                a[fr] = MFMA16(wf, xf[ks], a[fr]);
            }
        }
        #pragma unroll
        for (int fr = 0; fr < 4; ++fr) {
            f32x4 bb = *(const f32x4*)(bv + r0v + fr * 16 + 4 * g);
            #pragma unroll
            for (int r = 0; r < 4; ++r) {
                const int c = r0v + fr * 16 + 4 * g + r;
                vtile[c * 64 + (p ^ (((c >> 1) & 3) << 4))] = f2fp8(a[fr][r] + bb[r]);
            }
        }
    }
}

// ---------------------------------------------------------------------------
// Attention (R19, verified): 196 blocks x 1024 thr (16 waves), ONE barrier
// per j-tile; PV(it-1) + S(it) share the barrier region; ring-4 V/K depth-2.
// ---------------------------------------------------------------------------
__global__ __launch_bounds__(1024) void attn_mfma(
    const u16* __restrict__ qT, const u8* __restrict__ Kg,
    const u8* __restrict__ Vg, const float* __restrict__ x,
    const float* __restrict__ gamma_p, const float* __restrict__ qnorm,
    const float* __restrict__ kmax, float* __restrict__ out)
{
    __shared__ __align__(16) u8 smem[90112];
    u8* const Vl = smem;             // 4 x 16384
    u8* const Kl = smem + 65536;     // 4 x 4096
    u8* const Pl = smem + 81920;     // 2 x 4096 dbuf (reduce overlays after)

    const int t = threadIdx.x;
    const int w = t >> 6, li = t & 15, g = (t >> 4) & 3;
    const int jh = w & 3, qh = w >> 2;
    const int swz = ((li >> 1) & 3) << 4;

    const int b  = blockIdx.x / NJT;
    const int qt = blockIdx.x % NJT;
    const int i0 = qt * QT;

    const u16* qTb = qT + (size_t)b * N_SP * CQ;
    const u8*  Kbb = Kg + (size_t)b * N_SP * 64;
    const u8*  Vbb = Vg + (size_t)b * NJT * 16384;
    const float kmb = kmax[b];
    const f32x4 zero = {0.f, 0.f, 0.f, 0.f};

    const bf16x8 qf = *(const bf16x8*)(qTb + (size_t)(i0 + qh * 16 + li) * CQ + 8 * g);
    const float  mr = qnorm[b * N_SP + i0 + qh * 16 + li] * kmb;

    f32x4 acc[4];
    #pragma unroll
    for (int qq = 0; qq < 4; ++qq) acc[qq] = zero;
    float ls = 0.f;

    #define ISSUE(jt_, s_) do {                                               \
        dma16(Vbb + (size_t)(jt_) * 16384 + t * 16,                           \
              Vl + (s_) * 16384 + w * 1024);                                  \
        if (t < 256)                                                          \
            dma16(Kbb + (size_t)(jt_) * 4096 + t * 16,                        \
                  Kl + (s_) * 4096 + w * 1024);                               \
    } while (0)

    #define SPHASE(it_) do {                                                  \
        const u8* Kc_ = Kl + ((it_) & 3) * 4096;                              \
        bf16x8 kf_ = *(const bf16x8*)(Kc_ + (jh * 16 + li) * 64 + ((16 * g) ^ swz)); \
        f32x4 s_ = MFMA16(kf_, qf, zero);                                     \
        float a0_ = exp2f(s_[0] - mr), a1_ = exp2f(s_[1] - mr);               \
        float a2_ = exp2f(s_[2] - mr), a3_ = exp2f(s_[3] - mr);               \
        ls += (a0_ + a1_) + (a2_ + a3_);                                      \
        int pk_ = __builtin_amdgcn_cvt_pk_bf8_f32(a0_, a1_, 0, false);        \
        pk_ = __builtin_amdgcn_cvt_pk_bf8_f32(a2_, a3_, pk_, true);           \
        *(u32*)(Pl + ((it_) & 1) * 4096 + (qh * 16 + li) * 64 + (p0 ^ swz)) = (u32)pk_; \
    } while (0)

    #define PVPHASE(it_) do {                                                 \
        const u8* Pp_ = Pl + ((it_) & 1) * 4096;                              \
        const u8* Vc_ = Vl + ((it_) & 3) * 16384;                             \
        __builtin_amdgcn_s_setprio(1);                                        \
        l64x2 pa0_ = *(const l64x2*)(Pp_ + (0 * 16 + li) * 64 + ((16 * g) ^ swz)); \
        l64x2 pa1_ = *(const l64x2*)(Pp_ + (1 * 16 + li) * 64 + ((16 * g) ^ swz)); \
        l64x2 pa2_ = *(const l64x2*)(Pp_ + (2 * 16 + li) * 64 + ((16 * g) ^ swz)); \
        l64x2 pa3_ = *(const l64x2*)(Pp_ + (3 * 16 + li) * 64 + ((16 * g) ^ swz)); \
        l64x2 v0_  = *(const l64x2*)(Vc_ + (w * 16 + li) * 64 + ((16 * g) ^ swz)); \
        acc[0] = MFMA8(pa0_[0], v0_[0], acc[0]);                              \
        acc[1] = MFMA8(pa1_[0], v0_[0], acc[1]);                              \
        acc[2] = MFMA8(pa2_[0], v0_[0], acc[2]);                              \
        acc[3] = MFMA8(pa3_[0], v0_[0], acc[3]);                              \
        acc[0] = MFMA8(pa0_[1], v0_[1], acc[0]);                              \
        acc[1] = MFMA8(pa1_[1], v0_[1], acc[1]);                              \
        acc[2] = MFMA8(pa2_[1], v0_[1], acc[2]);                              \
        acc[3] = MFMA8(pa3_[1], v0_[1], acc[3]);                              \
        __builtin_amdgcn_s_setprio(0);                                        \
    } while (0)

    ISSUE(0, 0);
    ISSUE(1, 1);

    const int p0 = ((jh >> 1) & 1) * 8 + ((jh * 2 + (g >> 1)) & 3) * 16 + 4 * (g & 1);

    if (w < 4) asm volatile("s_waitcnt vmcnt(2) lgkmcnt(0)" ::: "memory");
    else       asm volatile("s_waitcnt vmcnt(1) lgkmcnt(0)" ::: "memory");
    __builtin_amdgcn_s_barrier();
    asm volatile("" ::: "memory");
    ISSUE(2, 2);
    SPHASE(0);

    for (int it = 1; it < NJT; ++it) {
        if (w < 4) asm volatile("s_waitcnt vmcnt(2) lgkmcnt(0)" ::: "memory");
        else       asm volatile("s_waitcnt vmcnt(1) lgkmcnt(0)" ::: "memory");
        __builtin_amdgcn_s_barrier();
        asm volatile("" ::: "memory");
        {
            int jn = it + 2; if (jn > NJT - 1) jn = NJT - 1;
            ISSUE(jn, (it + 2) & 3);
        }
        PVPHASE(it - 1);
        SPHASE(it);
    }

    asm volatile("s_waitcnt lgkmcnt(0)" ::: "memory");
    __builtin_amdgcn_s_barrier();
    asm volatile("" ::: "memory");
    PVPHASE(NJT - 1);
    #undef ISSUE
    #undef SPHASE
    #undef PVPHASE

    ls += __shfl_xor(ls, 16); ls += __shfl_xor(ls, 32);
    __syncthreads();
    float* red       = (float*)Pl;
    float* red_final = (float*)(Pl + 1024);
    if ((t & 63) < 16) red[w * 16 + li] = ls;
    __syncthreads();
    if (t < 64) {
        const int qh2 = t >> 4, l2 = t & 15;
        float s = red[(qh2 * 4 + 0) * 16 + l2] + red[(qh2 * 4 + 1) * 16 + l2]
                + red[(qh2 * 4 + 2) * 16 + l2] + red[(qh2 * 4 + 3) * 16 + l2];
        red_final[t] = s;
    }
    __syncthreads();

    const float gsc = gamma_p[0] * INV_BOUND;
    const int c = w * 16 + li;
    #pragma unroll
    for (int qq = 0; qq < 4; ++qq) {
        f32x4 lsv = *(const f32x4*)(red_final + qq * 16 + 4 * g);
        f32x4 rinv;
        #pragma unroll
        for (int r = 0; r < 4; ++r) rinv[r] = gsc / lsv[r];
        const size_t base = ((size_t)b * C_CH + c) * N_SP + i0 + qq * 16 + 4 * g;
        float4 xv = *(const float4*)(x + base);
        float4 o;
        o.x = acc[qq][0] * rinv[0] + xv.x;
        o.y = acc[qq][1] * rinv[1] + xv.y;
        o.z = acc[qq][2] * rinv[2] + xv.z;
        o.w = acc[qq][3] * rinv[3] + xv.w;
        *(float4*)(out + base) = o;
    }
}

// ---------------------------------------------------------------------------
extern "C" void kernel_launch(void* const* d_in, const int* in_sizes, int n_in,
                              void* d_out, int out_size, void* d_ws, size_t ws_size,
                              hipStream_t stream)
{
    const float* x  = (const float*)d_in[0];
    const float* Wq = (const float*)d_in[1];
    const float* bq = (const float*)d_in[2];
    const float* Wk = (const float*)d_in[3];
    const float* bk = (const float*)d_in[4];
    const float* Wv = (const float*)d_in[5];
    const float* bv = (const float*)d_in[6];
    const float* gm = (const float*)d_in[7];
    float* out = (float*)d_out;
    float* ws  = (float*)d_ws;

    float* scale = ws;                       // [0..3]
    float* kmax  = ws + 4;                   // [4..7]
    float* qnorm = ws + 8;                   // NB*N_SP
    u8* Wqb = (u8*)(ws + 8 + NB * N_SP);     // 16B-aligned
    u8* Wkb = Wqb + 32 * 512;
    u8* Wvb = Wkb + 32 * 512;
    u16* qT = (u16*)(Wvb + 256 * 512);
    u8* Kg  = (u8*)(qT + (size_t)NB * N_SP * CQ);
    u8* Vg  = Kg + (size_t)NB * N_SP * 64;

    stage0_kernel<<<81, 256, 0, stream>>>(Wq, Wk, Wv, Wqb, Wkb, Wvb, scale, kmax);
    qkv_fused<<<NB * NJT, 512, 0, stream>>>(x, Wqb, Wkb, Wvb, bq, bk, bv, scale, qT, Kg, Vg, qnorm, kmax);
    attn_mfma<<<NB * NJT, 1024, 0, stream>>>(qT, Kg, Vg, x, gm, qnorm, kmax, out);
}

// Round 21
// 79.702 us; speedup vs baseline: 1.1681x; 1.0203x over previous
//
#include <hip/hip_runtime.h>

#define N_SP 3136   // H*W = 49*64
#define C_CH 256
#define CQ   32
#define NB   4
#define JT   64     // attn j-tile
#define NJT  49     // j-tiles (exact)
#define QT   64     // attn q-tile (49 tiles exact)
// 1 / (exp(sqrt(3))*sqrt(3136/256) + 2*sqrt(6))
#define INV_BOUND 0.04051569f
#define LOG2E 1.44269504f

typedef __attribute__((ext_vector_type(8))) short bf16x8;
typedef __attribute__((ext_vector_type(4))) float f32x4;
typedef __attribute__((ext_vector_type(2))) long long l64x2;
typedef unsigned short u16;
typedef unsigned int   u32;
typedef unsigned char  u8;
typedef long long      l64;

#define MFMA16(a,b,c) __builtin_amdgcn_mfma_f32_16x16x32_bf16(a,b,c,0,0,0)
#define MFMA8(a,b,c)  __builtin_amdgcn_mfma_f32_16x16x32_bf8_fp8(a,b,c,0,0,0)

__device__ __forceinline__ u16 f2b(float f) {
    u32 u = __builtin_bit_cast(u32, f);
    u += 0x7fffu + ((u >> 16) & 1u);   // RTNE
    return (u16)(u >> 16);
}
__device__ __forceinline__ u8 f2fp8(float f) {
    return (u8)(__builtin_amdgcn_cvt_pk_fp8_f32(f, f, 0, false) & 0xff);
}
__device__ __forceinline__ void dma16(const void* g, void* l) {
    __builtin_amdgcn_global_load_lds((const __attribute__((address_space(1))) u32*)g,
                                     (__attribute__((address_space(3))) u32*)l, 16, 0, 0);
}

// ---------------------------------------------------------------------------
// stage0: W->bf16 pre-swizzled (blocks 0..79), norm+scale+kmax0 (block 80)
// ---------------------------------------------------------------------------
__global__ __launch_bounds__(256) void stage0_kernel(
    const float* __restrict__ Wq, const float* __restrict__ Wk,
    const float* __restrict__ Wv, u8* __restrict__ Wqb,
    u8* __restrict__ Wkb, u8* __restrict__ Wvb,
    float* __restrict__ scale_out, float* __restrict__ kmax)
{
    __shared__ float red[256];
    const int t = threadIdx.x;
    const int bid = blockIdx.x;

    if (bid < 80) {
        int idx = bid * 256 + t;
        const float* src; u8* dst; int off;
        if (idx < 2048)      { src = Wq; dst = Wqb; off = idx; }
        else if (idx < 4096) { src = Wk; dst = Wkb; off = idx - 2048; }
        else                 { src = Wv; dst = Wvb; off = idx - 4096; }
        float4 v = *(const float4*)(src + off * 4);
        ushort4 o; o.x = f2b(v.x); o.y = f2b(v.y); o.z = f2b(v.z); o.w = f2b(v.w);
        const int row = off >> 6, inner = (off & 63) * 8;
        *(ushort4*)(dst + row * 512 + (inner ^ ((row & 15) << 5))) = o;
    } else {
        if (t < NB) kmax[t] = 0.f;
        float u2 = 0.f;
        for (int i = t; i < CQ * C_CH; i += 256) { float w = Wq[i]; u2 += w * w; }
        red[t] = u2; __syncthreads();
        #pragma unroll
        for (int s = 128; s > 0; s >>= 1) { if (t < s) red[t] += red[t + s]; __syncthreads(); }
        float u2t = red[0]; __syncthreads();
        float vn2 = 0.f;
        for (int o = 0; o < CQ; ++o)   { float w = Wk[o * C_CH + t]; vn2 += w * w; }
        float wn2 = 0.f;
        for (int o = 0; o < C_CH; ++o) { float w = Wv[o * C_CH + t]; wn2 += w * w; }
        red[t] = fmaxf(vn2, wn2); __syncthreads();
        #pragma unroll
        for (int s = 128; s > 0; s >>= 1) { if (t < s) red[t] = fmaxf(red[t], red[t + s]); __syncthreads(); }
        if (t == 0) scale_out[0] = 1.0f / (sqrtf(u2t) * sqrtf(red[0]));
    }
}

// ---------------------------------------------------------------------------
// qkv_fused2: 196 blocks (b, nt) x 1024 thr (16 waves).
//  Phase A: transpose x-tile [256c][64n] -- ALL 4 slabs concurrently via 4
//           f32 staging tiles (2 barriers total); x read once from HBM.
//  DMA overlap: W0 (Wq|Wk) in flight during transpose; Wv[0:128] issued into
//  the dead ftile region during q/k; Wv[128:256] ping-pongs the same region.
//  q/k: waves 0-7 (verified R20 section-A body). V: 16 waves, 2 frags each.
// ---------------------------------------------------------------------------
__global__ __launch_bounds__(1024) void qkv_fused(
    const float* __restrict__ x, const u8* __restrict__ Wqb,
    const u8* __restrict__ Wkb, const u8* __restrict__ Wvb,
    const float* __restrict__ bq, const float* __restrict__ bk,
    const float* __restrict__ bv, const float* __restrict__ scale_p,
    u16* __restrict__ qT, u8* __restrict__ Kg, u8* __restrict__ Vg,
    float* __restrict__ qnorm, float* __restrict__ kmax)
{
    __shared__ __align__(16) u8 smem[132096];
    u8* const xTl = smem;                          // 32768: [64n][512B] swizzled
    u8* const FW  = smem + 32768;                  // 66560: ftile[4] -> Wv half
    u8* const W0  = smem + 99328;                  // 32768: Wq|Wk

    const int t = threadIdx.x;
    const int w = t >> 6, lane = t & 63, li = t & 15, g = (t >> 4) & 3;
    const int wq = w & 3;                          // n-group for compute
    const int b  = blockIdx.x / NJT;
    const int nt = blockIdx.x % NJT;
    const int n0 = nt * 64;
    const f32x4 zero = {0.f, 0.f, 0.f, 0.f};

    // ---- issue W0 (Wq|Wk, 32K): 2 dma16 per thread (uniform) ----
    #pragma unroll
    for (int k = 0; k < 2; ++k)
        dma16((k == 0 ? Wqb : Wkb) + t * 16, W0 + k * 16384 + w * 1024);

    // ---- Phase A: transpose 4 slabs concurrently ----
    {
        const int sl = t >> 8, tt = t & 255;
        const int c0 = sl * 64;
        float* ftile = (float*)(FW + sl * 16640);  // [64][65]
        const int cc = tt >> 4, nn4 = (tt & 15) * 4;
        #pragma unroll
        for (int k = 0; k < 4; ++k) {
            int cl = cc + k * 16;
            float4 v = *(const float4*)(x + (size_t)(b * C_CH + c0 + cl) * N_SP + n0 + nn4);
            ftile[cl * 65 + nn4]     = v.x;
            ftile[cl * 65 + nn4 + 1] = v.y;
            ftile[cl * 65 + nn4 + 2] = v.z;
            ftile[cl * 65 + nn4 + 3] = v.w;
        }
        __syncthreads();
        const int c4 = (tt & 15) * 4, nn = tt >> 4;
        #pragma unroll
        for (int k = 0; k < 4; ++k) {
            int nl = nn + k * 16;
            ushort4 o;
            o.x = f2b(ftile[(c4 + 0) * 65 + nl]);
            o.y = f2b(ftile[(c4 + 1) * 65 + nl]);
            o.z = f2b(ftile[(c4 + 2) * 65 + nl]);
            o.w = f2b(ftile[(c4 + 3) * 65 + nl]);
            *(ushort4*)(xTl + nl * 512 + (((c0 + c4) * 2) ^ ((nl & 15) << 5))) = o;
        }
    }
    __syncthreads();                               // ftile dead; xTl complete

    // ---- issue Wv[0:128] (64K) into FW: 4 dma16 per thread (uniform) ----
    #pragma unroll
    for (int k = 0; k < 4; ++k)
        dma16(Wvb + k * 16384 + t * 16, FW + k * 16384 + w * 1024);

    const int swz = li << 5;
    const int n = n0 + wq * 16 + li;
    bf16x8 xf[8];
    #pragma unroll
    for (int ks = 0; ks < 8; ++ks)
        xf[ks] = *(const bf16x8*)(xTl + (wq * 16 + li) * 512 + ((ks * 64 + 16 * g) ^ swz));

    // ---- q/k on waves 0-7 (W0 arrived: wait the 4 outstanding Wv DMAs) ----
    asm volatile("s_waitcnt vmcnt(4) lgkmcnt(0)" ::: "memory");
    __builtin_amdgcn_s_barrier();
    asm volatile("" ::: "memory");

    const int wh = w >> 2;
    if (w < 8) {
        if (wh == 0) {
            f32x4 aq0 = zero, aq1 = zero;
            #pragma unroll
            for (int ks = 0; ks < 8; ++ks) {
                const int o = (ks * 64 + 16 * g) ^ swz;
                bf16x8 w0 = *(const bf16x8*)(W0 + li * 512 + o);
                bf16x8 w1 = *(const bf16x8*)(W0 + (16 + li) * 512 + o);
                aq0 = MFMA16(w0, xf[ks], aq0);
                aq1 = MFMA16(w1, xf[ks], aq1);
            }
            const float scf = scale_p[0] * LOG2E;
            f32x4 bq0 = *(const f32x4*)(bq + 4 * g);
            f32x4 bq1 = *(const f32x4*)(bq + 16 + 4 * g);
            float qn2 = 0.f;
            ushort4 s0, s1;
            #pragma unroll
            for (int r = 0; r < 4; ++r) {
                float q0 = (aq0[r] + bq0[r]) * scf;
                float q1 = (aq1[r] + bq1[r]) * scf;
                qn2 += q0 * q0 + q1 * q1;
                ((u16*)&s0)[r] = f2b(q0); ((u16*)&s1)[r] = f2b(q1);
            }
            *(ushort4*)(qT + (size_t)(b * N_SP + n) * CQ + 4 * g)      = s0;
            *(ushort4*)(qT + (size_t)(b * N_SP + n) * CQ + 16 + 4 * g) = s1;
            qn2 += __shfl_xor(qn2, 16); qn2 += __shfl_xor(qn2, 32);
            if (g == 0) qnorm[b * N_SP + n] = sqrtf(qn2);
        } else {
            f32x4 ak0 = zero, ak1 = zero;
            #pragma unroll
            for (int ks = 0; ks < 8; ++ks) {
                const int o = (ks * 64 + 16 * g) ^ swz;
                bf16x8 w2 = *(const bf16x8*)(W0 + 16384 + li * 512 + o);
                bf16x8 w3 = *(const bf16x8*)(W0 + 16384 + (16 + li) * 512 + o);
                ak0 = MFMA16(w2, xf[ks], ak0);
                ak1 = MFMA16(w3, xf[ks], ak1);
            }
            f32x4 bk0 = *(const f32x4*)(bk + 4 * g);
            f32x4 bk1 = *(const f32x4*)(bk + 16 + 4 * g);
            float kn2 = 0.f;
            ushort4 s0, s1;
            #pragma unroll
            for (int r = 0; r < 4; ++r) {
                float k0 = ak0[r] + bk0[r];
                float k1 = ak1[r] + bk1[r];
                kn2 += k0 * k0 + k1 * k1;
                ((u16*)&s0)[r] = f2b(k0); ((u16*)&s1)[r] = f2b(k1);
            }
            u8* krow = Kg + ((size_t)b * N_SP + n) * 64;
            const int swn = ((n >> 1) & 3) << 4;
            *(ushort4*)(krow + ((8 * g) ^ swn))      = s0;
            *(ushort4*)(krow + ((32 + 8 * g) ^ swn)) = s1;
            kn2 += __shfl_xor(kn2, 16); kn2 += __shfl_xor(kn2, 32);
            float kn = sqrtf(kn2);
            #pragma unroll
            for (int d = 1; d < 16; d <<= 1) kn = fmaxf(kn, __shfl_xor(kn, d));
            if (lane == 0) atomicMax((int*)(kmax + b), __float_as_int(kn));
        }
    }

    // ---- V rows 0..127 on 16 waves (wait Wv0) ----
    asm volatile("s_waitcnt vmcnt(0)" ::: "memory");
    __builtin_amdgcn_s_barrier();
    asm volatile("" ::: "memory");

    const int jj = wq * 16 + li;
    const int p = ((jj >> 5) & 1) * 8 + ((jj >> 3) & 3) * 16 + (jj & 7);
    u8* vtile = Vg + (size_t)(b * NJT + nt) * 16384;
    const int vg = w >> 2;                         // 0..3: 32-row group
    {
        const int r0 = vg * 32;                    // rows in [0,128)
        f32x4 a[2] = {zero, zero};
        #pragma unroll
        for (int ks = 0; ks < 8; ++ks) {
            const int o = (ks * 64 + 16 * g) ^ swz;
            #pragma unroll
            for (int fr = 0; fr < 2; ++fr) {
                bf16x8 wf = *(const bf16x8*)(FW + (size_t)(r0 + fr * 16 + li) * 512 + o);
                a[fr] = MFMA16(wf, xf[ks], a[fr]);
            }
        }
        #pragma unroll
        for (int fr = 0; fr < 2; ++fr) {
            f32x4 bb = *(const f32x4*)(bv + r0 + fr * 16 + 4 * g);
            #pragma unroll
            for (int r = 0; r < 4; ++r) {
                const int c = r0 + fr * 16 + 4 * g + r;
                vtile[c * 64 + (p ^ (((c >> 1) & 3) << 4))] = f2fp8(a[fr][r] + bb[r]);
            }
        }
    }

    // ---- swap to Wv[128:256], then V rows 128..255 ----
    __syncthreads();
    #pragma unroll
    for (int k = 0; k < 4; ++k)
        dma16(Wvb + 65536 + k * 16384 + t * 16, FW + k * 16384 + w * 1024);
    asm volatile("s_waitcnt vmcnt(0)" ::: "memory");
    __syncthreads();
    {
        const int r0v = 128 + vg * 32;             // global V row base
        const int r0l = vg * 32;                   // row base within FW
        f32x4 a[2] = {zero, zero};
        #pragma unroll
        for (int ks = 0; ks < 8; ++ks) {
            const int o = (ks * 64 + 16 * g) ^ swz;
            #pragma unroll
            for (int fr = 0; fr < 2; ++fr) {
                bf16x8 wf = *(const bf16x8*)(FW + (size_t)(r0l + fr * 16 + li) * 512 + o);
                a[fr] = MFMA16(wf, xf[ks], a[fr]);
            }
        }
        #pragma unroll
        for (int fr = 0; fr < 2; ++fr) {
            f32x4 bb = *(const f32x4*)(bv + r0v + fr * 16 + 4 * g);
            #pragma unroll
            for (int r = 0; r < 4; ++r) {
                const int c = r0v + fr * 16 + 4 * g + r;
                vtile[c * 64 + (p ^ (((c >> 1) & 3) << 4))] = f2fp8(a[fr][r] + bb[r]);
            }
        }
    }
}

// ---------------------------------------------------------------------------
// Attention (R19, verified): 196 blocks x 1024 thr (16 waves), ONE barrier
// per j-tile; PV(it-1) + S(it) share the barrier region; ring-4 V/K depth-2.
// ---------------------------------------------------------------------------
__global__ __launch_bounds__(1024) void attn_mfma(
    const u16* __restrict__ qT, const u8* __restrict__ Kg,
    const u8* __restrict__ Vg, const float* __restrict__ x,
    const float* __restrict__ gamma_p, const float* __restrict__ qnorm,
    const float* __restrict__ kmax, float* __restrict__ out)
{
    __shared__ __align__(16) u8 smem[90112];
    u8* const Vl = smem;             // 4 x 16384
    u8* const Kl = smem + 65536;     // 4 x 4096
    u8* const Pl = smem + 81920;     // 2 x 4096 dbuf (reduce overlays after)

    const int t = threadIdx.x;
    const int w = t >> 6, li = t & 15, g = (t >> 4) & 3;
    const int jh = w & 3, qh = w >> 2;
    const int swz = ((li >> 1) & 3) << 4;

    const int b  = blockIdx.x / NJT;
    const int qt = blockIdx.x % NJT;
    const int i0 = qt * QT;

    const u16* qTb = qT + (size_t)b * N_SP * CQ;
    const u8*  Kbb = Kg + (size_t)b * N_SP * 64;
    const u8*  Vbb = Vg + (size_t)b * NJT * 16384;
    const float kmb = kmax[b];
    const f32x4 zero = {0.f, 0.f, 0.f, 0.f};

    const bf16x8 qf = *(const bf16x8*)(qTb + (size_t)(i0 + qh * 16 + li) * CQ + 8 * g);
    const float  mr = qnorm[b * N_SP + i0 + qh * 16 + li] * kmb;

    f32x4 acc[4];
    #pragma unroll
    for (int qq = 0; qq < 4; ++qq) acc[qq] = zero;
    float ls = 0.f;

    #define ISSUE(jt_, s_) do {                                               \
        dma16(Vbb + (size_t)(jt_) * 16384 + t * 16,                           \
              Vl + (s_) * 16384 + w * 1024);                                  \
        if (t < 256)                                                          \
            dma16(Kbb + (size_t)(jt_) * 4096 + t * 16,                        \
                  Kl + (s_) * 4096 + w * 1024);                               \
    } while (0)

    #define SPHASE(it_) do {                                                  \
        const u8* Kc_ = Kl + ((it_) & 3) * 4096;                              \
        bf16x8 kf_ = *(const bf16x8*)(Kc_ + (jh * 16 + li) * 64 + ((16 * g) ^ swz)); \
        f32x4 s_ = MFMA16(kf_, qf, zero);                                     \
        float a0_ = exp2f(s_[0] - mr), a1_ = exp2f(s_[1] - mr);               \
        float a2_ = exp2f(s_[2] - mr), a3_ = exp2f(s_[3] - mr);               \
        ls += (a0_ + a1_) + (a2_ + a3_);                                      \
        int pk_ = __builtin_amdgcn_cvt_pk_bf8_f32(a0_, a1_, 0, false);        \
        pk_ = __builtin_amdgcn_cvt_pk_bf8_f32(a2_, a3_, pk_, true);           \
        *(u32*)(Pl + ((it_) & 1) * 4096 + (qh * 16 + li) * 64 + (p0 ^ swz)) = (u32)pk_; \
    } while (0)

    #define PVPHASE(it_) do {                                                 \
        const u8* Pp_ = Pl + ((it_) & 1) * 4096;                              \
        const u8* Vc_ = Vl + ((it_) & 3) * 16384;                             \
        __builtin_amdgcn_s_setprio(1);                                        \
        l64x2 pa0_ = *(const l64x2*)(Pp_ + (0 * 16 + li) * 64 + ((16 * g) ^ swz)); \
        l64x2 pa1_ = *(const l64x2*)(Pp_ + (1 * 16 + li) * 64 + ((16 * g) ^ swz)); \
        l64x2 pa2_ = *(const l64x2*)(Pp_ + (2 * 16 + li) * 64 + ((16 * g) ^ swz)); \
        l64x2 pa3_ = *(const l64x2*)(Pp_ + (3 * 16 + li) * 64 + ((16 * g) ^ swz)); \
        l64x2 v0_  = *(const l64x2*)(Vc_ + (w * 16 + li) * 64 + ((16 * g) ^ swz)); \
        acc[0] = MFMA8(pa0_[0], v0_[0], acc[0]);                              \
        acc[1] = MFMA8(pa1_[0], v0_[0], acc[1]);                              \
        acc[2] = MFMA8(pa2_[0], v0_[0], acc[2]);                              \
        acc[3] = MFMA8(pa3_[0], v0_[0], acc[3]);                              \
        acc[0] = MFMA8(pa0_[1], v0_[1], acc[0]);                              \
        acc[1] = MFMA8(pa1_[1], v0_[1], acc[1]);                              \
        acc[2] = MFMA8(pa2_[1], v0_[1], acc[2]);                              \
        acc[3] = MFMA8(pa3_[1], v0_[1], acc[3]);                              \
        __builtin_amdgcn_s_setprio(0);                                        \
    } while (0)

    ISSUE(0, 0);
    ISSUE(1, 1);

    const int p0 = ((jh >> 1) & 1) * 8 + ((jh * 2 + (g >> 1)) & 3) * 16 + 4 * (g & 1);

    if (w < 4) asm volatile("s_waitcnt vmcnt(2) lgkmcnt(0)" ::: "memory");
    else       asm volatile("s_waitcnt vmcnt(1) lgkmcnt(0)" ::: "memory");
    __builtin_amdgcn_s_barrier();
    asm volatile("" ::: "memory");
    ISSUE(2, 2);
    SPHASE(0);

    for (int it = 1; it < NJT; ++it) {
        if (w < 4) asm volatile("s_waitcnt vmcnt(2) lgkmcnt(0)" ::: "memory");
        else       asm volatile("s_waitcnt vmcnt(1) lgkmcnt(0)" ::: "memory");
        __builtin_amdgcn_s_barrier();
        asm volatile("" ::: "memory");
        {
            int jn = it + 2; if (jn > NJT - 1) jn = NJT - 1;
            ISSUE(jn, (it + 2) & 3);
        }
        PVPHASE(it - 1);
        SPHASE(it);
    }

    asm volatile("s_waitcnt lgkmcnt(0)" ::: "memory");
    __builtin_amdgcn_s_barrier();
    asm volatile("" ::: "memory");
    PVPHASE(NJT - 1);
    #undef ISSUE
    #undef SPHASE
    #undef PVPHASE

    ls += __shfl_xor(ls, 16); ls += __shfl_xor(ls, 32);
    __syncthreads();
    float* red       = (float*)Pl;
    float* red_final = (float*)(Pl + 1024);
    if ((t & 63) < 16) red[w * 16 + li] = ls;
    __syncthreads();
    if (t < 64) {
        const int qh2 = t >> 4, l2 = t & 15;
        float s = red[(qh2 * 4 + 0) * 16 + l2] + red[(qh2 * 4 + 1) * 16 + l2]
                + red[(qh2 * 4 + 2) * 16 + l2] + red[(qh2 * 4 + 3) * 16 + l2];
        red_final[t] = s;
    }
    __syncthreads();

    const float gsc = gamma_p[0] * INV_BOUND;
    const int c = w * 16 + li;
    #pragma unroll
    for (int qq = 0; qq < 4; ++qq) {
        f32x4 lsv = *(const f32x4*)(red_final + qq * 16 + 4 * g);
        f32x4 rinv;
        #pragma unroll
        for (int r = 0; r < 4; ++r) rinv[r] = gsc / lsv[r];
        const size_t base = ((size_t)b * C_CH + c) * N_SP + i0 + qq * 16 + 4 * g;
        float4 xv = *(const float4*)(x + base);
        float4 o;
        o.x = acc[qq][0] * rinv[0] + xv.x;
        o.y = acc[qq][1] * rinv[1] + xv.y;
        o.z = acc[qq][2] * rinv[2] + xv.z;
        o.w = acc[qq][3] * rinv[3] + xv.w;
        *(float4*)(out + base) = o;
    }
}

// ---------------------------------------------------------------------------
extern "C" void kernel_launch(void* const* d_in, const int* in_sizes, int n_in,
                              void* d_out, int out_size, void* d_ws, size_t ws_size,
                              hipStream_t stream)
{
    const float* x  = (const float*)d_in[0];
    const float* Wq = (const float*)d_in[1];
    const float* bq = (const float*)d_in[2];
    const float* Wk = (const float*)d_in[3];
    const float* bk = (const float*)d_in[4];
    const float* Wv = (const float*)d_in[5];
    const float* bv = (const float*)d_in[6];
    const float* gm = (const float*)d_in[7];
    float* out = (float*)d_out;
    float* ws  = (float*)d_ws;

    float* scale = ws;                       // [0..3]
    float* kmax  = ws + 4;                   // [4..7]
    float* qnorm = ws + 8;                   // NB*N_SP
    u8* Wqb = (u8*)(ws + 8 + NB * N_SP);     // 16B-aligned
    u8* Wkb = Wqb + 32 * 512;
    u8* Wvb = Wkb + 32 * 512;
    u16* qT = (u16*)(Wvb + 256 * 512);
    u8* Kg  = (u8*)(qT + (size_t)NB * N_SP * CQ);
    u8* Vg  = Kg + (size_t)NB * N_SP * 64;

    stage0_kernel<<<81, 256, 0, stream>>>(Wq, Wk, Wv, Wqb, Wkb, Wvb, scale, kmax);
    qkv_fused<<<NB * NJT, 1024, 0, stream>>>(x, Wqb, Wkb, Wvb, bq, bk, bv, scale, qT, Kg, Vg, qnorm, kmax);
    attn_mfma<<<NB * NJT, 1024, 0, stream>>>(qT, Kg, Vg, x, gm, qnorm, kmax, out);
}